// Round 1
// baseline (7371.214 us; speedup 1.0000x reference)
//
#include <hip/hip_runtime.h>
#include <math.h>

#define HH 512
#define WW 512
constexpr int CC = 64;   // hidden channels
constexpr int BB = 2;    // batch

// ---------------- conv 7x7, Cin=6 -> 64, pad 3, + ReLU ----------------
__global__ __launch_bounds__(256)
void conv7_relu_k(const float* __restrict__ in, const float* __restrict__ wt,
                  float* __restrict__ out)
{
    const int w0 = blockIdx.x * 32, h0 = blockIdx.y * 8, b = blockIdx.z;
    const int tw = threadIdx.x & 31, th = threadIdx.x >> 5;
    const int w = w0 + tw, h = h0 + th;
    const size_t HW = (size_t)HH * WW;
    const float* inb = in + (size_t)b * 6 * HW;

    float acc[CC];
#pragma unroll
    for (int co = 0; co < CC; ++co) acc[co] = 0.f;

    const bool interior = (h0 >= 3) && (h0 + 8 + 3 <= HH) && (w0 >= 3) && (w0 + 32 + 3 <= WW);

    for (int ci = 0; ci < 6; ++ci) {
        const float* inc = inb + (size_t)ci * HW;
        for (int dh = 0; dh < 7; ++dh) {
            const int hh = h + dh - 3;
            float iv[7];
            if (interior) {
#pragma unroll
                for (int dw = 0; dw < 7; ++dw) iv[dw] = inc[hh * WW + (w + dw - 3)];
            } else {
#pragma unroll
                for (int dw = 0; dw < 7; ++dw) {
                    const int w2 = w + dw - 3;
                    iv[dw] = (hh >= 0 && hh < HH && w2 >= 0 && w2 < WW)
                                 ? inc[hh * WW + w2] : 0.f;
                }
            }
#pragma unroll
            for (int co = 0; co < CC; ++co) {
                const float* wp = wt + (((co * 6 + ci) * 7 + dh) * 7);
#pragma unroll
                for (int dw = 0; dw < 7; ++dw)
                    acc[co] = fmaf(iv[dw], wp[dw], acc[co]);
            }
        }
    }

    const size_t ob = (size_t)b * CC * HW + (size_t)h * WW + w;
#pragma unroll
    for (int co = 0; co < CC; ++co)
        out[ob + (size_t)co * HW] = fmaxf(acc[co], 0.f);
}

// ---------------- conv 3x3, Cin=64 -> COUT, pad 1, optional BN/ReLU/skip-add ----------------
template <int COUT, bool BN, bool RELU, bool ADD>
__global__ __launch_bounds__(256)
void conv3_k(const float* __restrict__ in, const float* __restrict__ wt,
             const float* __restrict__ g, const float* __restrict__ be,
             const float* __restrict__ mn, const float* __restrict__ vr,
             float* __restrict__ out)
{
    const int w0 = blockIdx.x * 32, h0 = blockIdx.y * 8, b = blockIdx.z;
    const int tw = threadIdx.x & 31, th = threadIdx.x >> 5;
    const int w = w0 + tw, h = h0 + th;
    const size_t HW = (size_t)HH * WW;
    const float* inb = in + (size_t)b * CC * HW;

    float acc[COUT];
#pragma unroll
    for (int co = 0; co < COUT; ++co) acc[co] = 0.f;

    const bool interior = (h0 >= 1) && (h0 + 8 + 1 <= HH) && (w0 >= 1) && (w0 + 32 + 1 <= WW);

    for (int ci = 0; ci < CC; ++ci) {
        const float* inc = inb + (size_t)ci * HW;
        float iv[9];
        if (interior) {
#pragma unroll
            for (int dh = 0; dh < 3; ++dh)
#pragma unroll
                for (int dw = 0; dw < 3; ++dw)
                    iv[dh * 3 + dw] = inc[(h + dh - 1) * WW + (w + dw - 1)];
        } else {
#pragma unroll
            for (int dh = 0; dh < 3; ++dh) {
                const int hh = h + dh - 1;
#pragma unroll
                for (int dw = 0; dw < 3; ++dw) {
                    const int w2 = w + dw - 1;
                    iv[dh * 3 + dw] = (hh >= 0 && hh < HH && w2 >= 0 && w2 < WW)
                                          ? inc[hh * WW + w2] : 0.f;
                }
            }
        }
#pragma unroll
        for (int co = 0; co < COUT; ++co) {
            const float* wp = wt + ((size_t)co * CC + ci) * 9;
#pragma unroll
            for (int k = 0; k < 9; ++k)
                acc[co] = fmaf(iv[k], wp[k], acc[co]);
        }
    }

    const size_t ob = (size_t)b * COUT * HW + (size_t)h * WW + w;
#pragma unroll
    for (int co = 0; co < COUT; ++co) {
        float v = acc[co];
        if (BN) {
            const float s  = g[co] * rsqrtf(vr[co] + 1e-5f);
            const float bi = be[co] - mn[co] * s;
            v = fmaf(v, s, bi);
        }
        if (RELU) v = fmaxf(v, 0.f);
        if (ADD)  v += out[ob + (size_t)co * HW];
        out[ob + (size_t)co * HW] = v;
    }
}

// ---------------- vertical adaptive filter: softmax(wl[c*10 .. c*10+4]) over K, taps along H ----------------
__global__ __launch_bounds__(256)
void filt_v_k(const float* __restrict__ wl, const float* __restrict__ base,
              float* __restrict__ outF)
{
    const int idx = blockIdx.x * 256 + threadIdx.x;
    const int w = idx & (WW - 1);
    const int h = (idx >> 9) & (HH - 1);
    const int bc = idx >> 18;            // 0..5 : b*3 + c
    const int b = bc / 3, c = bc % 3;
    const size_t HW = (size_t)HH * WW;

    const float* wp = wl + (size_t)(b * 30 + c * 10) * HW + (size_t)h * WW + w;
    float v[5];
    float mx = -1e30f;
#pragma unroll
    for (int i = 0; i < 5; ++i) { v[i] = wp[(size_t)i * HW]; mx = fmaxf(mx, v[i]); }
    float s = 0.f;
#pragma unroll
    for (int i = 0; i < 5; ++i) { v[i] = __expf(v[i] - mx); s += v[i]; }
    const float inv = 1.f / s;

    const float* bp = base + (size_t)bc * HW + w;
    float acc = 0.f;
#pragma unroll
    for (int i = 0; i < 5; ++i) {
        const int hh = h + i - 2;
        const float bv = (hh >= 0 && hh < HH) ? bp[(size_t)hh * WW] : 0.f;
        acc = fmaf(bv, v[i] * inv, acc);
    }
    outF[(size_t)bc * HW + (size_t)h * WW + w] = acc;
}

// ---------------- horizontal adaptive filter: softmax(wl[c*10+5 .. c*10+9]), taps along W ----------------
__global__ __launch_bounds__(256)
void filt_h_k(const float* __restrict__ wl, const float* __restrict__ filtF,
              float* __restrict__ out)
{
    const int idx = blockIdx.x * 256 + threadIdx.x;
    const int w = idx & (WW - 1);
    const int h = (idx >> 9) & (HH - 1);
    const int bc = idx >> 18;
    const int b = bc / 3, c = bc % 3;
    const size_t HW = (size_t)HH * WW;

    const float* wp = wl + (size_t)(b * 30 + c * 10 + 5) * HW + (size_t)h * WW + w;
    float v[5];
    float mx = -1e30f;
#pragma unroll
    for (int i = 0; i < 5; ++i) { v[i] = wp[(size_t)i * HW]; mx = fmaxf(mx, v[i]); }
    float s = 0.f;
#pragma unroll
    for (int i = 0; i < 5; ++i) { v[i] = __expf(v[i] - mx); s += v[i]; }
    const float inv = 1.f / s;

    const float* fp = filtF + (size_t)bc * HW + (size_t)h * WW;
    float acc = 0.f;
#pragma unroll
    for (int i = 0; i < 5; ++i) {
        const int w2 = w + i - 2;
        const float fv = (w2 >= 0 && w2 < WW) ? fp[w2] : 0.f;
        acc = fmaf(fv, v[i] * inv, acc);
    }
    out[(size_t)bc * HW + (size_t)h * WW + w] = acc;
}

extern "C" void kernel_launch(void* const* d_in, const int* in_sizes, int n_in,
                              void* d_out, int out_size, void* d_ws, size_t ws_size,
                              hipStream_t stream)
{
    const float* fm      = (const float*)d_in[0];
    const float* base    = (const float*)d_in[1];
    const float* w_first = (const float*)d_in[2];
    const float* kb_w1   = (const float*)d_in[3];
    const float* kb_g1   = (const float*)d_in[4];
    const float* kb_b1   = (const float*)d_in[5];
    const float* kb_m1   = (const float*)d_in[6];
    const float* kb_v1   = (const float*)d_in[7];
    const float* kb_w2   = (const float*)d_in[8];
    const float* kb_g2   = (const float*)d_in[9];
    const float* kb_b2   = (const float*)d_in[10];
    const float* kb_m2   = (const float*)d_in[11];
    const float* kb_v2   = (const float*)d_in[12];
    const float* w_last  = (const float*)d_in[13];
    float* out = (float*)d_out;

    const size_t HW = (size_t)HH * WW;
    float* A  = (float*)d_ws;                 // 2*64*512*512 floats = 134 MB
    float* Bb = A + (size_t)BB * CC * HW;     // second 134 MB buffer

    dim3 blk(256);
    dim3 grd(WW / 32, HH / 8, BB);

    // conv_first + ReLU -> A
    conv7_relu_k<<<grd, blk, 0, stream>>>(fm, w_first, A);

    // 4 residual blocks
    for (int i = 0; i < 4; ++i) {
        conv3_k<64, true, true, false><<<grd, blk, 0, stream>>>(
            A, kb_w1 + (size_t)i * 64 * 64 * 9,
            kb_g1 + i * 64, kb_b1 + i * 64, kb_m1 + i * 64, kb_v1 + i * 64, Bb);
        conv3_k<64, true, true, true><<<grd, blk, 0, stream>>>(
            Bb, kb_w2 + (size_t)i * 64 * 64 * 9,
            kb_g2 + i * 64, kb_b2 + i * 64, kb_m2 + i * 64, kb_v2 + i * 64, A);
    }

    // conv_last: 64 -> 30, no BN/ReLU -> Bb
    conv3_k<30, false, false, false><<<grd, blk, 0, stream>>>(
        A, w_last, nullptr, nullptr, nullptr, nullptr, Bb);

    // adaptive filtering: vertical then horizontal
    float* F = A;  // reuse A (free after conv_last consumed it)
    const int npix = BB * 3 * HH * WW;
    filt_v_k<<<npix / 256, blk, 0, stream>>>(Bb, base, F);
    filt_h_k<<<npix / 256, blk, 0, stream>>>(Bb, F, out);
}

// Round 2
// 2090.026 us; speedup vs baseline: 3.5269x; 3.5269x over previous
//
#include <hip/hip_runtime.h>
#include <math.h>

typedef __attribute__((ext_vector_type(8))) short short8;
typedef __attribute__((ext_vector_type(4))) float float4v;

__device__ __forceinline__ unsigned short f2bf(float f) {
    union { float f; unsigned u; } x; x.f = f;
    unsigned r = x.u + 0x7FFFu + ((x.u >> 16) & 1u);
    return (unsigned short)(r >> 16);
}
__device__ __forceinline__ float bf2f(unsigned short u) {
    union { unsigned u; float f; } x; x.u = ((unsigned)u) << 16;
    return x.f;
}

// ---------------- conv 7x7, Cin=6 -> 64, pad 3, + ReLU, f32 direct, NHWC bf16 out ----------------
__global__ __launch_bounds__(256)
void conv7_relu_k(const float* __restrict__ in, const float* __restrict__ wt,
                  unsigned short* __restrict__ out)
{
    const int w0 = blockIdx.x * 32, h0 = blockIdx.y * 8, b = blockIdx.z;
    const int tw = threadIdx.x & 31, th = threadIdx.x >> 5;
    const int w = w0 + tw, h = h0 + th;
    const size_t HW = (size_t)512 * 512;
    const float* inb = in + (size_t)b * 6 * HW;

    float acc[64];
#pragma unroll
    for (int co = 0; co < 64; ++co) acc[co] = 0.f;

    const bool interior = (h0 >= 3) && (h0 + 8 + 3 <= 512) && (w0 >= 3) && (w0 + 32 + 3 <= 512);

    for (int ci = 0; ci < 6; ++ci) {
        const float* inc = inb + (size_t)ci * HW;
        for (int dh = 0; dh < 7; ++dh) {
            const int hh = h + dh - 3;
            float iv[7];
            if (interior) {
#pragma unroll
                for (int dw = 0; dw < 7; ++dw) iv[dw] = inc[hh * 512 + (w + dw - 3)];
            } else {
#pragma unroll
                for (int dw = 0; dw < 7; ++dw) {
                    const int w2 = w + dw - 3;
                    iv[dw] = (hh >= 0 && hh < 512 && w2 >= 0 && w2 < 512)
                                 ? inc[hh * 512 + w2] : 0.f;
                }
            }
#pragma unroll
            for (int co = 0; co < 64; ++co) {
                const float* wp = wt + (((co * 6 + ci) * 7 + dh) * 7);
#pragma unroll
                for (int dw = 0; dw < 7; ++dw)
                    acc[co] = fmaf(iv[dw], wp[dw], acc[co]);
            }
        }
    }

    const size_t obase = ((((size_t)b * 512 + h) * 512) + w) * 64;
#pragma unroll
    for (int q = 0; q < 8; ++q) {
        uint4 pk;
        pk.x = (unsigned)f2bf(fmaxf(acc[q*8+0], 0.f)) | ((unsigned)f2bf(fmaxf(acc[q*8+1], 0.f)) << 16);
        pk.y = (unsigned)f2bf(fmaxf(acc[q*8+2], 0.f)) | ((unsigned)f2bf(fmaxf(acc[q*8+3], 0.f)) << 16);
        pk.z = (unsigned)f2bf(fmaxf(acc[q*8+4], 0.f)) | ((unsigned)f2bf(fmaxf(acc[q*8+5], 0.f)) << 16);
        pk.w = (unsigned)f2bf(fmaxf(acc[q*8+6], 0.f)) | ((unsigned)f2bf(fmaxf(acc[q*8+7], 0.f)) << 16);
        *(uint4*)(out + obase + q * 8) = pk;
    }
}

// ---------------- weight repack: OIHW f32 -> fragment-linear bf16 ----------------
// dst[((kk*4+cot)*64+lane)*8+j] = w[co=cot*16+(lane&15)][ci=(kk&1)*32+(lane>>4)*8+j][s=kk>>1]
__global__ __launch_bounds__(256)
void repack3_k(const float* __restrict__ w1, const float* __restrict__ w2,
               unsigned short* __restrict__ dst)
{
    const int conv = blockIdx.z;
    const float* src = (conv < 4) ? (w1 + (size_t)conv * 36864) : (w2 + (size_t)(conv - 4) * 36864);
    unsigned short* d = dst + (size_t)conv * 36864;
    const int t = blockIdx.x * 256 + threadIdx.x;   // < 36864
    const int j = t & 7, l = (t >> 3) & 63, ct = (t >> 9) & 3, kk = t >> 11;
    const int co = ct * 16 + (l & 15);
    const int ci = (kk & 1) * 32 + (l >> 4) * 8 + j;
    const int s  = kk >> 1;
    d[t] = f2bf(src[((size_t)co * 64 + ci) * 9 + s]);
}

__global__ __launch_bounds__(256)
void repackL_k(const float* __restrict__ wsrc, unsigned short* __restrict__ d)
{
    const int t = blockIdx.x * 256 + threadIdx.x;   // < 18432
    const int j = t & 7, l = (t >> 3) & 63, ct = (t >> 9) & 1, kk = t >> 10;
    const int co = ct * 16 + (l & 15);
    const int ci = (kk & 1) * 32 + (l >> 4) * 8 + j;
    const int s  = kk >> 1;
    d[t] = (co < 30) ? f2bf(wsrc[((size_t)co * 64 + ci) * 9 + s]) : (unsigned short)0;
}

// ---------------- conv 3x3 implicit-GEMM MFMA: NHWC bf16 in/out ----------------
// block: 256 thr = 4 waves; tile: 2 rows x 128 cols x (NCOT*16) cout
// LDS: weights NCOT*18432 B (fragment-linear) + patch 4x130x8 groups x16B (XOR swizzled)
template <int NCOT, int OC, bool BN_, bool RELU_, bool ADD_>
__global__ __launch_bounds__(256)
void conv3_mfma(const unsigned short* __restrict__ in,
                const unsigned short* __restrict__ wrp,
                const float* __restrict__ g, const float* __restrict__ be,
                const float* __restrict__ mn, const float* __restrict__ vr,
                const unsigned short* __restrict__ skip,
                unsigned short* __restrict__ out)
{
    extern __shared__ char smem[];
    unsigned short* w_lds = (unsigned short*)smem;
    char* p_lds = smem + NCOT * 18 * 64 * 16;

    const int b  = blockIdx.z;
    const int h0 = blockIdx.y * 2;
    const int w0 = blockIdx.x * 128;
    const int tid = threadIdx.x;
    const int wv = tid >> 6, l = tid & 63, lq = l >> 4, lr = l & 15;

    // stage weights (already fragment-linear in global)
    for (int i = tid; i < NCOT * 18 * 64; i += 256)
        ((int4*)w_lds)[i] = ((const int4*)wrp)[i];

    // stage input patch: rows h0-1..h0+2, cols w0-1..w0+128, 64 ci as 8x16B groups
    for (int idx = tid; idx < 4 * 130 * 8; idx += 256) {
        const int G = idx & 7;
        const int c = (idx >> 3) % 130;
        const int r = idx / 1040;
        const int hh = h0 - 1 + r, wc = w0 - 1 + c;
        int4 v = make_int4(0, 0, 0, 0);
        if (hh >= 0 && hh < 512 && wc >= 0 && wc < 512)
            v = *(const int4*)(in + ((((size_t)b * 512 + hh) * 512) + wc) * 64 + G * 8);
        *(int4*)(p_lds + ((r * 130 + c) * 8 + (G ^ (c & 7))) * 16) = v;
    }
    __syncthreads();

    float4v acc[2][2][NCOT];
#pragma unroll
    for (int pr = 0; pr < 2; ++pr)
#pragma unroll
        for (int pb = 0; pb < 2; ++pb)
#pragma unroll
            for (int ct = 0; ct < NCOT; ++ct)
                acc[pr][pb][ct] = (float4v){0.f, 0.f, 0.f, 0.f};

    const int cbase = wv * 32 + lr;
#pragma unroll
    for (int kk = 0; kk < 18; ++kk) {
        const int s = kk >> 1, dh = s / 3, dwd = s % 3, g0 = (kk & 1) * 4;
        short8 a[2][2];
#pragma unroll
        for (int pr = 0; pr < 2; ++pr)
#pragma unroll
            for (int pb = 0; pb < 2; ++pb) {
                const int r = pr + dh;
                const int c = cbase + pb * 16 + dwd;
                const int G = (g0 + lq) ^ (c & 7);
                a[pr][pb] = *(const short8*)(p_lds + ((r * 130 + c) * 8 + G) * 16);
            }
#pragma unroll
        for (int ct = 0; ct < NCOT; ++ct) {
            const short8 bw = *(const short8*)((const char*)w_lds + ((kk * NCOT + ct) * 64 + l) * 16);
#pragma unroll
            for (int pr = 0; pr < 2; ++pr)
#pragma unroll
                for (int pb = 0; pb < 2; ++pb)
                    acc[pr][pb][ct] = __builtin_amdgcn_mfma_f32_16x16x32_bf16(
                        a[pr][pb], bw, acc[pr][pb][ct], 0, 0, 0);
        }
    }

    float sc[NCOT], bi[NCOT];
#pragma unroll
    for (int ct = 0; ct < NCOT; ++ct) {
        if (BN_) {
            const int co = ct * 16 + lr;
            const float s2 = g[co] * rsqrtf(vr[co] + 1e-5f);
            sc[ct] = s2; bi[ct] = be[co] - mn[co] * s2;
        } else { sc[ct] = 1.f; bi[ct] = 0.f; }
    }

#pragma unroll
    for (int pr = 0; pr < 2; ++pr) {
        const size_t rowb = (((size_t)b * 512) + (h0 + pr)) * 512;
#pragma unroll
        for (int pb = 0; pb < 2; ++pb) {
            const int col0 = w0 + wv * 32 + pb * 16 + lq * 4;
#pragma unroll
            for (int ct = 0; ct < NCOT; ++ct) {
                const int co = ct * 16 + lr;
                if (co < OC) {
#pragma unroll
                    for (int rg = 0; rg < 4; ++rg) {
                        float v = acc[pr][pb][ct][rg];
                        if (BN_) v = v * sc[ct] + bi[ct];
                        if (RELU_) v = fmaxf(v, 0.f);
                        const size_t o = (rowb + (col0 + rg)) * OC + co;
                        if (ADD_) v += bf2f(skip[o]);
                        out[o] = f2bf(v);
                    }
                }
            }
        }
    }
}

// ---------------- vertical adaptive filter ----------------
__global__ __launch_bounds__(256)
void filt_v_k(const unsigned short* __restrict__ wl, const float* __restrict__ base,
              float* __restrict__ outF)
{
    const int idx = blockIdx.x * 256 + threadIdx.x;
    const int w = idx & 511;
    const int h = (idx >> 9) & 511;
    const int bc = idx >> 18;            // b*3 + c
    const int b = bc / 3, c = bc % 3;
    const size_t HW = (size_t)512 * 512;

    const unsigned short* wp = wl + ((((size_t)b * 512 + h) * 512) + w) * 30 + c * 10;
    float v[5]; float mx = -1e30f;
#pragma unroll
    for (int i = 0; i < 5; ++i) { v[i] = bf2f(wp[i]); mx = fmaxf(mx, v[i]); }
    float s = 0.f;
#pragma unroll
    for (int i = 0; i < 5; ++i) { v[i] = __expf(v[i] - mx); s += v[i]; }
    const float inv = 1.f / s;

    const float* bp = base + (size_t)bc * HW + w;
    float acc = 0.f;
#pragma unroll
    for (int i = 0; i < 5; ++i) {
        const int hh = h + i - 2;
        const float bv = (hh >= 0 && hh < 512) ? bp[(size_t)hh * 512] : 0.f;
        acc = fmaf(bv, v[i] * inv, acc);
    }
    outF[(size_t)bc * HW + (size_t)h * 512 + w] = acc;
}

// ---------------- horizontal adaptive filter ----------------
__global__ __launch_bounds__(256)
void filt_h_k(const unsigned short* __restrict__ wl, const float* __restrict__ filtF,
              float* __restrict__ out)
{
    const int idx = blockIdx.x * 256 + threadIdx.x;
    const int w = idx & 511;
    const int h = (idx >> 9) & 511;
    const int bc = idx >> 18;
    const int b = bc / 3, c = bc % 3;
    const size_t HW = (size_t)512 * 512;

    const unsigned short* wp = wl + ((((size_t)b * 512 + h) * 512) + w) * 30 + c * 10 + 5;
    float v[5]; float mx = -1e30f;
#pragma unroll
    for (int i = 0; i < 5; ++i) { v[i] = bf2f(wp[i]); mx = fmaxf(mx, v[i]); }
    float s = 0.f;
#pragma unroll
    for (int i = 0; i < 5; ++i) { v[i] = __expf(v[i] - mx); s += v[i]; }
    const float inv = 1.f / s;

    const float* fp = filtF + (size_t)bc * HW + (size_t)h * 512;
    float acc = 0.f;
#pragma unroll
    for (int i = 0; i < 5; ++i) {
        const int w2 = w + i - 2;
        const float fv = (w2 >= 0 && w2 < 512) ? fp[w2] : 0.f;
        acc = fmaf(fv, v[i] * inv, acc);
    }
    out[(size_t)bc * HW + (size_t)h * 512 + w] = acc;
}

extern "C" void kernel_launch(void* const* d_in, const int* in_sizes, int n_in,
                              void* d_out, int out_size, void* d_ws, size_t ws_size,
                              hipStream_t stream)
{
    const float* fm      = (const float*)d_in[0];
    const float* base    = (const float*)d_in[1];
    const float* w_first = (const float*)d_in[2];
    const float* kb_w1   = (const float*)d_in[3];
    const float* kb_g1   = (const float*)d_in[4];
    const float* kb_b1   = (const float*)d_in[5];
    const float* kb_m1   = (const float*)d_in[6];
    const float* kb_v1   = (const float*)d_in[7];
    const float* kb_w2   = (const float*)d_in[8];
    const float* kb_g2   = (const float*)d_in[9];
    const float* kb_b2   = (const float*)d_in[10];
    const float* kb_m2   = (const float*)d_in[11];
    const float* kb_v2   = (const float*)d_in[12];
    const float* w_last  = (const float*)d_in[13];

    char* ws = (char*)d_ws;
    unsigned short* wrp3 = (unsigned short*)ws;                       // 8*36864 bf16
    unsigned short* wrpL = wrp3 + (size_t)8 * 36864;                  // 18432 bf16
    unsigned short* actA = (unsigned short*)(ws + (1 << 20));
    unsigned short* actB = actA + (size_t)2 * 512 * 512 * 64;
    unsigned short* actC = actB + (size_t)2 * 512 * 512 * 64;
    unsigned short* logits = actC + (size_t)2 * 512 * 512 * 64;
    float* F = (float*)(logits + (size_t)2 * 512 * 512 * 30);

    hipFuncSetAttribute((const void*)conv3_mfma<4, 64, true, true, false>,
                        hipFuncAttributeMaxDynamicSharedMemorySize, 140288);
    hipFuncSetAttribute((const void*)conv3_mfma<4, 64, true, true, true>,
                        hipFuncAttributeMaxDynamicSharedMemorySize, 140288);
    hipFuncSetAttribute((const void*)conv3_mfma<2, 30, false, false, false>,
                        hipFuncAttributeMaxDynamicSharedMemorySize, 103424);

    dim3 blk(256);

    // weight repacks
    repack3_k<<<dim3(144, 1, 8), blk, 0, stream>>>(kb_w1, kb_w2, wrp3);
    repackL_k<<<dim3(72, 1, 1), blk, 0, stream>>>(w_last, wrpL);

    // conv_first (f32 direct) -> actA (NHWC bf16)
    conv7_relu_k<<<dim3(16, 64, 2), blk, 0, stream>>>(fm, w_first, actA);

    // residual blocks (MFMA)
    dim3 g3(4, 256, 2);
    unsigned short* cur = actA;
    unsigned short* oth = actC;
    for (int i = 0; i < 4; ++i) {
        conv3_mfma<4, 64, true, true, false><<<g3, blk, 140288, stream>>>(
            cur, wrp3 + (size_t)i * 36864,
            kb_g1 + i * 64, kb_b1 + i * 64, kb_m1 + i * 64, kb_v1 + i * 64,
            nullptr, actB);
        conv3_mfma<4, 64, true, true, true><<<g3, blk, 140288, stream>>>(
            actB, wrp3 + (size_t)(4 + i) * 36864,
            kb_g2 + i * 64, kb_b2 + i * 64, kb_m2 + i * 64, kb_v2 + i * 64,
            cur, oth);
        unsigned short* t = cur; cur = oth; oth = t;
    }

    // conv_last: 64 -> 30 (MFMA, 2 co-tiles) -> logits (NHWC30 bf16)
    conv3_mfma<2, 30, false, false, false><<<g3, blk, 103424, stream>>>(
        cur, wrpL, nullptr, nullptr, nullptr, nullptr, nullptr, logits);

    // adaptive filtering
    filt_v_k<<<6144, blk, 0, stream>>>(logits, base, F);
    filt_h_k<<<6144, blk, 0, stream>>>(logits, F, (float*)d_out);
}

// Round 3
// 1286.827 us; speedup vs baseline: 5.7282x; 1.6242x over previous
//
#include <hip/hip_runtime.h>
#include <math.h>

typedef __attribute__((ext_vector_type(8))) short short8;
typedef __attribute__((ext_vector_type(4))) float float4v;

__device__ __forceinline__ unsigned short f2bf(float f) {
    union { float f; unsigned u; } x; x.f = f;
    unsigned r = x.u + 0x7FFFu + ((x.u >> 16) & 1u);
    return (unsigned short)(r >> 16);
}
__device__ __forceinline__ float bf2f(unsigned short u) {
    union { unsigned u; float f; } x; x.u = ((unsigned)u) << 16;
    return x.f;
}

// ---------------- input prep: NCHW f32 (Cin=6) -> NHWC8 bf16 hi + lo planes ----------------
__global__ __launch_bounds__(256)
void prep7_k(const float* __restrict__ in, unsigned short* __restrict__ hi,
             unsigned short* __restrict__ lo)
{
    const int idx = blockIdx.x * 256 + threadIdx.x;   // < 2*512*512
    const int b = idx >> 18, rem = idx & 262143;
    const int h = rem >> 9, w = rem & 511;
    const size_t HW = (size_t)512 * 512;
    unsigned short vh[8], vl[8];
#pragma unroll
    for (int c = 0; c < 8; ++c) {
        float x = (c < 6) ? in[((size_t)(b * 6 + c)) * HW + (h << 9) + w] : 0.f;
        unsigned short h16 = f2bf(x);
        vh[c] = h16;
        vl[c] = f2bf(x - bf2f(h16));
    }
    const size_t o = ((size_t)idx) * 8;
    *(uint4*)(hi + o) = *(uint4*)vh;
    *(uint4*)(lo + o) = *(uint4*)vl;
}

// ---------------- conv7 weight repack: (64,6,7,7) f32 -> fragment-linear bf16 hi/lo ----------------
// dst[((kk*4+ct)*64+l)*8+j]: co=ct*16+(l&15), slot s=kk*4+(l>>4), ci=j; zero if s>=49 or j>=6
__global__ __launch_bounds__(256)
void repack7_k(const float* __restrict__ wsrc, unsigned short* __restrict__ dhi,
               unsigned short* __restrict__ dlo)
{
    const int t = blockIdx.x * 256 + threadIdx.x;   // < 26624
    if (t >= 26624) return;
    const int j = t & 7, l = (t >> 3) & 63, ct = (t >> 9) & 3, kk = t >> 11;
    const int co = ct * 16 + (l & 15);
    const int s = kk * 4 + (l >> 4);
    float v = 0.f;
    if (s < 49 && j < 6)
        v = wsrc[((size_t)(co * 6 + j) * 7 + s / 7) * 7 + s % 7];
    unsigned short h16 = f2bf(v);
    dhi[t] = h16;
    dlo[t] = f2bf(v - bf2f(h16));
}

// ---------------- conv 7x7 MFMA implicit GEMM, split precision, + ReLU, NHWC64 bf16 out ----------
// block 256 = 4 waves; tile 2 rows x 128 cols x 64 co; K = 13 steps (52 slots x 8 ci)
__global__ __launch_bounds__(256)
void conv7_mfma(const unsigned short* __restrict__ inhi,
                const unsigned short* __restrict__ inlo,
                const unsigned short* __restrict__ whi,
                const unsigned short* __restrict__ wlo,
                unsigned short* __restrict__ out)
{
    extern __shared__ char p_lds[];   // [2 planes][8 rows][134 cols][16B]

    const int b  = blockIdx.z;
    const int h0 = blockIdx.y * 2;
    const int w0 = blockIdx.x * 128;
    const int tid = threadIdx.x;
    const int wv = tid >> 6, l = tid & 63, lq = l >> 4, lr = l & 15;

    for (int idx = tid; idx < 2144; idx += 256) {   // 2*8*134
        const int plane = idx >= 1072;
        const int rc = plane ? idx - 1072 : idx;
        const int r = rc / 134, c = rc % 134;
        const int hh = h0 - 3 + r, wc = w0 - 3 + c;
        int4 v = make_int4(0, 0, 0, 0);
        if (hh >= 0 && hh < 512 && wc >= 0 && wc < 512) {
            const unsigned short* src = plane ? inlo : inhi;
            v = *(const int4*)(src + ((((size_t)b * 512 + hh) * 512) + wc) * 8);
        }
        *(int4*)(p_lds + (size_t)idx * 16) = v;
    }
    __syncthreads();

    float4v acc[2][2][4];
#pragma unroll
    for (int pr = 0; pr < 2; ++pr)
#pragma unroll
        for (int pb = 0; pb < 2; ++pb)
#pragma unroll
            for (int ct = 0; ct < 4; ++ct)
                acc[pr][pb][ct] = (float4v){0.f, 0.f, 0.f, 0.f};

    const int cbase = wv * 32 + lr;
#pragma unroll
    for (int kk = 0; kk < 13; ++kk) {
        int s = kk * 4 + lq;
        if (s > 48) s = 48;              // padded slots: weights are zero
        const int dh = s / 7, dwd = s % 7;
        short8 ah[2][2], al[2][2];
#pragma unroll
        for (int pr = 0; pr < 2; ++pr)
#pragma unroll
            for (int pb = 0; pb < 2; ++pb) {
                const int off = ((pr + dh) * 134 + cbase + pb * 16 + dwd) * 16;
                ah[pr][pb] = *(const short8*)(p_lds + off);
                al[pr][pb] = *(const short8*)(p_lds + 17152 + off);
            }
#pragma unroll
        for (int ct = 0; ct < 4; ++ct) {
            const short8 bh = *(const short8*)(whi + ((size_t)(kk * 4 + ct) * 64 + l) * 8);
            const short8 bl = *(const short8*)(wlo + ((size_t)(kk * 4 + ct) * 64 + l) * 8);
#pragma unroll
            for (int pr = 0; pr < 2; ++pr)
#pragma unroll
                for (int pb = 0; pb < 2; ++pb) {
                    acc[pr][pb][ct] = __builtin_amdgcn_mfma_f32_16x16x32_bf16(ah[pr][pb], bh, acc[pr][pb][ct], 0, 0, 0);
                    acc[pr][pb][ct] = __builtin_amdgcn_mfma_f32_16x16x32_bf16(al[pr][pb], bh, acc[pr][pb][ct], 0, 0, 0);
                    acc[pr][pb][ct] = __builtin_amdgcn_mfma_f32_16x16x32_bf16(ah[pr][pb], bl, acc[pr][pb][ct], 0, 0, 0);
                }
        }
    }

#pragma unroll
    for (int pr = 0; pr < 2; ++pr) {
        const size_t rowb = (((size_t)b * 512) + (h0 + pr)) * 512;
#pragma unroll
        for (int pb = 0; pb < 2; ++pb) {
            const int col0 = w0 + wv * 32 + pb * 16 + lq * 4;
#pragma unroll
            for (int ct = 0; ct < 4; ++ct) {
                const int co = ct * 16 + lr;
#pragma unroll
                for (int rg = 0; rg < 4; ++rg) {
                    const size_t o = (rowb + (col0 + rg)) * 64 + co;
                    out[o] = f2bf(fmaxf(acc[pr][pb][ct][rg], 0.f));
                }
            }
        }
    }
}

// ---------------- conv3 weight repack: OIHW f32 -> fragment-linear bf16 ----------------
__global__ __launch_bounds__(256)
void repack3_k(const float* __restrict__ w1, const float* __restrict__ w2,
               unsigned short* __restrict__ dst)
{
    const int conv = blockIdx.z;
    const float* src = (conv < 4) ? (w1 + (size_t)conv * 36864) : (w2 + (size_t)(conv - 4) * 36864);
    unsigned short* d = dst + (size_t)conv * 36864;
    const int t = blockIdx.x * 256 + threadIdx.x;   // < 36864
    const int j = t & 7, l = (t >> 3) & 63, ct = (t >> 9) & 3, kk = t >> 11;
    const int co = ct * 16 + (l & 15);
    const int ci = (kk & 1) * 32 + (l >> 4) * 8 + j;
    const int s  = kk >> 1;
    d[t] = f2bf(src[((size_t)co * 64 + ci) * 9 + s]);
}

__global__ __launch_bounds__(256)
void repackL_k(const float* __restrict__ wsrc, unsigned short* __restrict__ d)
{
    const int t = blockIdx.x * 256 + threadIdx.x;   // < 18432
    const int j = t & 7, l = (t >> 3) & 63, ct = (t >> 9) & 1, kk = t >> 10;
    const int co = ct * 16 + (l & 15);
    const int ci = (kk & 1) * 32 + (l >> 4) * 8 + j;
    const int s  = kk >> 1;
    d[t] = (co < 30) ? f2bf(wsrc[((size_t)co * 64 + ci) * 9 + s]) : (unsigned short)0;
}

// ---------------- conv 3x3 implicit-GEMM MFMA: NHWC bf16 in/out, weights from global ----------
// block 256 = 4 waves; tile 2 rows x 128 cols x (NCOT*16) co; LDS = input patch only (65 KB)
template <int NCOT, int OC, bool BN_, bool RELU_, bool ADD_>
__global__ __launch_bounds__(256)
void conv3_mfma(const unsigned short* __restrict__ in,
                const unsigned short* __restrict__ wrp,
                const float* __restrict__ g, const float* __restrict__ be,
                const float* __restrict__ mn, const float* __restrict__ vr,
                const unsigned short* __restrict__ skip,
                unsigned short* __restrict__ out)
{
    extern __shared__ char p_lds[];   // [4 rows][130 cols][8 groups][16B], G xor-swizzled

    const int b  = blockIdx.z;
    const int h0 = blockIdx.y * 2;
    const int w0 = blockIdx.x * 128;
    const int tid = threadIdx.x;
    const int wv = tid >> 6, l = tid & 63, lq = l >> 4, lr = l & 15;

    for (int idx = tid; idx < 4 * 130 * 8; idx += 256) {
        const int G = idx & 7;
        const int c = (idx >> 3) % 130;
        const int r = idx / 1040;
        const int hh = h0 - 1 + r, wc = w0 - 1 + c;
        int4 v = make_int4(0, 0, 0, 0);
        if (hh >= 0 && hh < 512 && wc >= 0 && wc < 512)
            v = *(const int4*)(in + ((((size_t)b * 512 + hh) * 512) + wc) * 64 + G * 8);
        *(int4*)(p_lds + ((r * 130 + c) * 8 + (G ^ (c & 7))) * 16) = v;
    }
    __syncthreads();

    float4v acc[2][2][NCOT];
#pragma unroll
    for (int pr = 0; pr < 2; ++pr)
#pragma unroll
        for (int pb = 0; pb < 2; ++pb)
#pragma unroll
            for (int ct = 0; ct < NCOT; ++ct)
                acc[pr][pb][ct] = (float4v){0.f, 0.f, 0.f, 0.f};

    const int cbase = wv * 32 + lr;
#pragma unroll
    for (int kk = 0; kk < 18; ++kk) {
        const int s = kk >> 1, dh = s / 3, dwd = s % 3, g0 = (kk & 1) * 4;
        short8 a[2][2];
#pragma unroll
        for (int pr = 0; pr < 2; ++pr)
#pragma unroll
            for (int pb = 0; pb < 2; ++pb) {
                const int r = pr + dh;
                const int c = cbase + pb * 16 + dwd;
                const int G = (g0 + lq) ^ (c & 7);
                a[pr][pb] = *(const short8*)(p_lds + ((r * 130 + c) * 8 + G) * 16);
            }
#pragma unroll
        for (int ct = 0; ct < NCOT; ++ct) {
            const short8 bw = *(const short8*)(wrp + ((size_t)(kk * NCOT + ct) * 64 + l) * 8);
#pragma unroll
            for (int pr = 0; pr < 2; ++pr)
#pragma unroll
                for (int pb = 0; pb < 2; ++pb)
                    acc[pr][pb][ct] = __builtin_amdgcn_mfma_f32_16x16x32_bf16(
                        a[pr][pb], bw, acc[pr][pb][ct], 0, 0, 0);
        }
    }

    float sc[NCOT], bi[NCOT];
#pragma unroll
    for (int ct = 0; ct < NCOT; ++ct) {
        if (BN_) {
            const int co = ct * 16 + lr;
            const float s2 = g[co] * rsqrtf(vr[co] + 1e-5f);
            sc[ct] = s2; bi[ct] = be[co] - mn[co] * s2;
        } else { sc[ct] = 1.f; bi[ct] = 0.f; }
    }

#pragma unroll
    for (int pr = 0; pr < 2; ++pr) {
        const size_t rowb = (((size_t)b * 512) + (h0 + pr)) * 512;
#pragma unroll
        for (int pb = 0; pb < 2; ++pb) {
            const int col0 = w0 + wv * 32 + pb * 16 + lq * 4;
#pragma unroll
            for (int ct = 0; ct < NCOT; ++ct) {
                const int co = ct * 16 + lr;
                if (co < OC) {
#pragma unroll
                    for (int rg = 0; rg < 4; ++rg) {
                        float v = acc[pr][pb][ct][rg];
                        if (BN_) v = v * sc[ct] + bi[ct];
                        if (RELU_) v = fmaxf(v, 0.f);
                        const size_t o = (rowb + (col0 + rg)) * OC + co;
                        if (ADD_) v += bf2f(skip[o]);
                        out[o] = f2bf(v);
                    }
                }
            }
        }
    }
}

// ---------------- vertical adaptive filter ----------------
__global__ __launch_bounds__(256)
void filt_v_k(const unsigned short* __restrict__ wl, const float* __restrict__ base,
              float* __restrict__ outF)
{
    const int idx = blockIdx.x * 256 + threadIdx.x;
    const int w = idx & 511;
    const int h = (idx >> 9) & 511;
    const int bc = idx >> 18;
    const int b = bc / 3, c = bc % 3;
    const size_t HW = (size_t)512 * 512;

    const unsigned short* wp = wl + ((((size_t)b * 512 + h) * 512) + w) * 30 + c * 10;
    float v[5]; float mx = -1e30f;
#pragma unroll
    for (int i = 0; i < 5; ++i) { v[i] = bf2f(wp[i]); mx = fmaxf(mx, v[i]); }
    float s = 0.f;
#pragma unroll
    for (int i = 0; i < 5; ++i) { v[i] = __expf(v[i] - mx); s += v[i]; }
    const float inv = 1.f / s;

    const float* bp = base + (size_t)bc * HW + w;
    float acc = 0.f;
#pragma unroll
    for (int i = 0; i < 5; ++i) {
        const int hh = h + i - 2;
        const float bv = (hh >= 0 && hh < 512) ? bp[(size_t)hh * 512] : 0.f;
        acc = fmaf(bv, v[i] * inv, acc);
    }
    outF[(size_t)bc * HW + (size_t)h * 512 + w] = acc;
}

// ---------------- horizontal adaptive filter ----------------
__global__ __launch_bounds__(256)
void filt_h_k(const unsigned short* __restrict__ wl, const float* __restrict__ filtF,
              float* __restrict__ out)
{
    const int idx = blockIdx.x * 256 + threadIdx.x;
    const int w = idx & 511;
    const int h = (idx >> 9) & 511;
    const int bc = idx >> 18;
    const int b = bc / 3, c = bc % 3;
    const size_t HW = (size_t)512 * 512;

    const unsigned short* wp = wl + ((((size_t)b * 512 + h) * 512) + w) * 30 + c * 10 + 5;
    float v[5]; float mx = -1e30f;
#pragma unroll
    for (int i = 0; i < 5; ++i) { v[i] = bf2f(wp[i]); mx = fmaxf(mx, v[i]); }
    float s = 0.f;
#pragma unroll
    for (int i = 0; i < 5; ++i) { v[i] = __expf(v[i] - mx); s += v[i]; }
    const float inv = 1.f / s;

    const float* fp = filtF + (size_t)bc * HW + (size_t)h * 512;
    float acc = 0.f;
#pragma unroll
    for (int i = 0; i < 5; ++i) {
        const int w2 = w + i - 2;
        const float fv = (w2 >= 0 && w2 < 512) ? fp[w2] : 0.f;
        acc = fmaf(fv, v[i] * inv, acc);
    }
    out[(size_t)bc * HW + (size_t)h * 512 + w] = acc;
}

extern "C" void kernel_launch(void* const* d_in, const int* in_sizes, int n_in,
                              void* d_out, int out_size, void* d_ws, size_t ws_size,
                              hipStream_t stream)
{
    const float* fm      = (const float*)d_in[0];
    const float* base    = (const float*)d_in[1];
    const float* w_first = (const float*)d_in[2];
    const float* kb_w1   = (const float*)d_in[3];
    const float* kb_g1   = (const float*)d_in[4];
    const float* kb_b1   = (const float*)d_in[5];
    const float* kb_m1   = (const float*)d_in[6];
    const float* kb_v1   = (const float*)d_in[7];
    const float* kb_w2   = (const float*)d_in[8];
    const float* kb_g2   = (const float*)d_in[9];
    const float* kb_b2   = (const float*)d_in[10];
    const float* kb_m2   = (const float*)d_in[11];
    const float* kb_v2   = (const float*)d_in[12];
    const float* w_last  = (const float*)d_in[13];

    char* ws = (char*)d_ws;
    unsigned short* wrp3   = (unsigned short*)ws;                 // 589824 B
    unsigned short* wrpL   = wrp3 + (size_t)8 * 36864;            // 36864 B
    unsigned short* wrp7hi = wrpL + 18432;                        // 53248 B
    unsigned short* wrp7lo = wrp7hi + 26624;                      // 53248 B
    unsigned short* actA = (unsigned short*)(ws + (1 << 20));     // 67 MB each
    unsigned short* actB = actA + (size_t)2 * 512 * 512 * 64;
    unsigned short* actC = actB + (size_t)2 * 512 * 512 * 64;
    unsigned short* in7hi = actB;                                 // dead once conv7 done
    unsigned short* in7lo = actB + (size_t)2 * 512 * 512 * 8;
    unsigned short* logits = actC;                                // dead buffers by then
    float* F = (float*)actB;

    hipFuncSetAttribute((const void*)conv3_mfma<4, 64, true, true, false>,
                        hipFuncAttributeMaxDynamicSharedMemorySize, 66560);
    hipFuncSetAttribute((const void*)conv3_mfma<4, 64, true, true, true>,
                        hipFuncAttributeMaxDynamicSharedMemorySize, 66560);
    hipFuncSetAttribute((const void*)conv3_mfma<2, 30, false, false, false>,
                        hipFuncAttributeMaxDynamicSharedMemorySize, 66560);
    hipFuncSetAttribute((const void*)conv7_mfma,
                        hipFuncAttributeMaxDynamicSharedMemorySize, 34304);

    dim3 blk(256);

    // weight repacks + input prep
    repack3_k<<<dim3(144, 1, 8), blk, 0, stream>>>(kb_w1, kb_w2, wrp3);
    repackL_k<<<dim3(72, 1, 1), blk, 0, stream>>>(w_last, wrpL);
    repack7_k<<<dim3(104, 1, 1), blk, 0, stream>>>(w_first, wrp7hi, wrp7lo);
    prep7_k<<<dim3(2048, 1, 1), blk, 0, stream>>>(fm, in7hi, in7lo);

    // conv_first (MFMA split-precision) -> actA
    conv7_mfma<<<dim3(4, 256, 2), blk, 34304, stream>>>(in7hi, in7lo, wrp7hi, wrp7lo, actA);

    // residual blocks (MFMA)
    dim3 g3(4, 256, 2);
    unsigned short* cur = actA;
    unsigned short* oth = actC;
    for (int i = 0; i < 4; ++i) {
        conv3_mfma<4, 64, true, true, false><<<g3, blk, 66560, stream>>>(
            cur, wrp3 + (size_t)i * 36864,
            kb_g1 + i * 64, kb_b1 + i * 64, kb_m1 + i * 64, kb_v1 + i * 64,
            nullptr, actB);
        conv3_mfma<4, 64, true, true, true><<<g3, blk, 66560, stream>>>(
            actB, wrp3 + (size_t)(4 + i) * 36864,
            kb_g2 + i * 64, kb_b2 + i * 64, kb_m2 + i * 64, kb_v2 + i * 64,
            cur, oth);
        unsigned short* t = cur; cur = oth; oth = t;
    }

    // conv_last: 64 -> 30 -> logits (NHWC30 bf16)
    conv3_mfma<2, 30, false, false, false><<<g3, blk, 66560, stream>>>(
        cur, wrpL, nullptr, nullptr, nullptr, nullptr, nullptr, logits);

    // adaptive filtering
    filt_v_k<<<6144, blk, 0, stream>>>(logits, base, F);
    filt_h_k<<<6144, blk, 0, stream>>>(logits, F, (float*)d_out);
}

// Round 4
// 868.358 us; speedup vs baseline: 8.4887x; 1.4819x over previous
//
#include <hip/hip_runtime.h>
#include <math.h>

typedef __attribute__((ext_vector_type(8))) short short8;
typedef __attribute__((ext_vector_type(4))) float float4v;

__device__ __forceinline__ unsigned short f2bf(float f) {
    union { float f; unsigned u; } x; x.f = f;
    unsigned r = x.u + 0x7FFFu + ((x.u >> 16) & 1u);
    return (unsigned short)(r >> 16);
}
__device__ __forceinline__ float bf2f(unsigned short u) {
    union { unsigned u; float f; } x; x.u = ((unsigned)u) << 16;
    return x.f;
}

#define HWSZ ((size_t)512 * 512)

// ---------------- input prep: NCHW f32 (Cin=6) -> NHWC8 bf16 hi + lo planes ----------------
__global__ __launch_bounds__(256)
void prep7_k(const float* __restrict__ in, unsigned short* __restrict__ hi,
             unsigned short* __restrict__ lo)
{
    const int idx = blockIdx.x * 256 + threadIdx.x;   // < 2*512*512
    const int b = idx >> 18, rem = idx & 262143;
    const int h = rem >> 9, w = rem & 511;
    unsigned short vh[8], vl[8];
#pragma unroll
    for (int c = 0; c < 8; ++c) {
        float x = (c < 6) ? in[((size_t)(b * 6 + c)) * HWSZ + (h << 9) + w] : 0.f;
        unsigned short h16 = f2bf(x);
        vh[c] = h16;
        vl[c] = f2bf(x - bf2f(h16));
    }
    const size_t o = ((size_t)idx) * 8;
    *(uint4*)(hi + o) = *(uint4*)vh;
    *(uint4*)(lo + o) = *(uint4*)vl;
}

// ---------------- conv7 weight repack: (64,6,7,7) f32 -> fragment-linear bf16 hi/lo ----------------
__global__ __launch_bounds__(256)
void repack7_k(const float* __restrict__ wsrc, unsigned short* __restrict__ dhi,
               unsigned short* __restrict__ dlo)
{
    const int t = blockIdx.x * 256 + threadIdx.x;   // < 26624
    if (t >= 26624) return;
    const int j = t & 7, l = (t >> 3) & 63, ct = (t >> 9) & 3, kk = t >> 11;
    const int co = ct * 16 + (l & 15);
    const int s = kk * 4 + (l >> 4);
    float v = 0.f;
    if (s < 49 && j < 6)
        v = wsrc[((size_t)(co * 6 + j) * 7 + s / 7) * 7 + s % 7];
    unsigned short h16 = f2bf(v);
    dhi[t] = h16;
    dlo[t] = f2bf(v - bf2f(h16));
}

// ---------------- conv 7x7 MFMA implicit GEMM, split precision, + ReLU ----------------
// out: split-plane NHWC32 bf16  [b][2][512][512][32]
__global__ __launch_bounds__(256)
void conv7_mfma(const unsigned short* __restrict__ inhi,
                const unsigned short* __restrict__ inlo,
                const unsigned short* __restrict__ whi,
                const unsigned short* __restrict__ wlo,
                unsigned short* __restrict__ out)
{
    extern __shared__ char p_lds[];   // [2 planes][8 rows][134 cols][16B]

    const int id = blockIdx.x;                      // 2048 blocks
    const int lid = (id & 7) * 256 + (id >> 3);     // XCD chunk swizzle
    const int w0 = (lid & 3) * 128;
    const int rest = lid >> 2;
    const int h0 = (rest & 255) * 2;
    const int b  = rest >> 8;

    const int tid = threadIdx.x;
    const int wv = tid >> 6, l = tid & 63, lq = l >> 4, lr = l & 15;

    for (int idx = tid; idx < 2144; idx += 256) {   // 2*8*134
        const int plane = idx >= 1072;
        const int rc = plane ? idx - 1072 : idx;
        const int r = rc / 134, c = rc % 134;
        const int hh = h0 - 3 + r, wc = w0 - 3 + c;
        int4 v = make_int4(0, 0, 0, 0);
        if (hh >= 0 && hh < 512 && wc >= 0 && wc < 512) {
            const unsigned short* src = plane ? inlo : inhi;
            v = *(const int4*)(src + ((((size_t)b * 512 + hh) * 512) + wc) * 8);
        }
        *(int4*)(p_lds + (size_t)idx * 16) = v;
    }
    __syncthreads();

    float4v acc[2][2][4];
#pragma unroll
    for (int pr = 0; pr < 2; ++pr)
#pragma unroll
        for (int pb = 0; pb < 2; ++pb)
#pragma unroll
            for (int ct = 0; ct < 4; ++ct)
                acc[pr][pb][ct] = (float4v){0.f, 0.f, 0.f, 0.f};

    const int cbase = wv * 32 + lr;
#pragma unroll
    for (int kk = 0; kk < 13; ++kk) {
        int s = kk * 4 + lq;
        if (s > 48) s = 48;              // padded slots: weights are zero
        const int dh = s / 7, dwd = s % 7;
        short8 ah[2][2], al[2][2];
#pragma unroll
        for (int pr = 0; pr < 2; ++pr)
#pragma unroll
            for (int pb = 0; pb < 2; ++pb) {
                const int off = ((pr + dh) * 134 + cbase + pb * 16 + dwd) * 16;
                ah[pr][pb] = *(const short8*)(p_lds + off);
                al[pr][pb] = *(const short8*)(p_lds + 17152 + off);
            }
#pragma unroll
        for (int ct = 0; ct < 4; ++ct) {
            const short8 bh = *(const short8*)(whi + ((size_t)(kk * 4 + ct) * 64 + l) * 8);
            const short8 bl = *(const short8*)(wlo + ((size_t)(kk * 4 + ct) * 64 + l) * 8);
#pragma unroll
            for (int pr = 0; pr < 2; ++pr)
#pragma unroll
                for (int pb = 0; pb < 2; ++pb) {
                    acc[pr][pb][ct] = __builtin_amdgcn_mfma_f32_16x16x32_bf16(ah[pr][pb], bh, acc[pr][pb][ct], 0, 0, 0);
                    acc[pr][pb][ct] = __builtin_amdgcn_mfma_f32_16x16x32_bf16(al[pr][pb], bh, acc[pr][pb][ct], 0, 0, 0);
                    acc[pr][pb][ct] = __builtin_amdgcn_mfma_f32_16x16x32_bf16(ah[pr][pb], bl, acc[pr][pb][ct], 0, 0, 0);
                }
        }
    }

#pragma unroll
    for (int pr = 0; pr < 2; ++pr) {
        const int h = h0 + pr;
#pragma unroll
        for (int pb = 0; pb < 2; ++pb) {
            const int col0 = w0 + wv * 32 + pb * 16 + lq * 4;
#pragma unroll
            for (int ct = 0; ct < 4; ++ct) {
                const int half = ct >> 1, colocal = (ct & 1) * 16 + lr;
#pragma unroll
                for (int rg = 0; rg < 4; ++rg) {
                    const size_t o = ((((size_t)(b * 2 + half) * 512 + h) * 512) + (col0 + rg)) * 32 + colocal;
                    out[o] = f2bf(fmaxf(acc[pr][pb][ct][rg], 0.f));
                }
            }
        }
    }
}

// ---------------- conv3 weight repack: OIHW f32 -> phase-major fragment-linear bf16 ----------------
// storage slot kk_s = half*9 + s ; entry [((kk_s*4+ct)*64+l)*8+j]
__global__ __launch_bounds__(256)
void repack3_k(const float* __restrict__ w1, const float* __restrict__ w2,
               unsigned short* __restrict__ dst)
{
    const int conv = blockIdx.z;
    const float* src = (conv < 4) ? (w1 + (size_t)conv * 36864) : (w2 + (size_t)(conv - 4) * 36864);
    unsigned short* d = dst + (size_t)conv * 36864;
    const int t = blockIdx.x * 256 + threadIdx.x;   // < 36864
    const int j = t & 7, l = (t >> 3) & 63, ct = (t >> 9) & 3, kks = t >> 11;
    const int hf = kks / 9, s = kks % 9;
    const int co = ct * 16 + (l & 15);
    const int ci = hf * 32 + (l >> 4) * 8 + j;
    d[t] = f2bf(src[((size_t)co * 64 + ci) * 9 + s]);
}

__global__ __launch_bounds__(256)
void repackL_k(const float* __restrict__ wsrc, unsigned short* __restrict__ d)
{
    const int t = blockIdx.x * 256 + threadIdx.x;   // < 18432
    const int j = t & 7, l = (t >> 3) & 63, ct = (t >> 9) & 1, kks = t >> 10;
    const int hf = kks / 9, s = kks % 9;
    const int co = ct * 16 + (l & 15);
    const int ci = hf * 32 + (l >> 4) * 8 + j;
    d[t] = (co < 30) ? f2bf(wsrc[((size_t)co * 64 + ci) * 9 + s]) : (unsigned short)0;
}

// ---------------- conv 3x3 implicit-GEMM MFMA, ci-split 2-phase ----------------
// in/skip: split-plane NHWC32 bf16. out: split-plane NHWC32 (PLANAR_=false) or planar30 bf16.
// block 256 = 4 waves; tile 2 rows x 128 cols; LDS = weights-half + patch-half (70 KB @ NCOT=4)
template <int NCOT, int OC, bool BN_, bool RELU_, bool ADD_, bool PLANAR_>
__global__ __launch_bounds__(256)
void conv3_mfma(const unsigned short* __restrict__ in,
                const unsigned short* __restrict__ wrp,
                const float* __restrict__ g, const float* __restrict__ be,
                const float* __restrict__ mn, const float* __restrict__ vr,
                const unsigned short* __restrict__ skip,
                unsigned short* __restrict__ out)
{
    extern __shared__ char smem[];
    unsigned short* w_lds = (unsigned short*)smem;            // NCOT*9*1024 B per phase
    char* p_lds = smem + NCOT * 9 * 1024;                     // 4 planes x 521 granules x 16 B

    const int id = blockIdx.x;                      // 2048 blocks
    const int lid = (id & 7) * 256 + (id >> 3);     // XCD chunk swizzle
    const int w0 = (lid & 3) * 128;
    const int rest = lid >> 2;
    const int h0 = (rest & 255) * 2;
    const int b  = rest >> 8;

    const int tid = threadIdx.x;
    const int wv = tid >> 6, l = tid & 63, lq = l >> 4, lr = l & 15;
    const int cbase = wv * 32 + lr;

    float4v acc[2][2][NCOT];
#pragma unroll
    for (int pr = 0; pr < 2; ++pr)
#pragma unroll
        for (int pb = 0; pb < 2; ++pb)
#pragma unroll
            for (int ct = 0; ct < NCOT; ++ct)
                acc[pr][pb][ct] = (float4v){0.f, 0.f, 0.f, 0.f};

    for (int ph = 0; ph < 2; ++ph) {
        // ---- stage weight half (fragment-linear, contiguous) ----
        const int4* wsrc = (const int4*)(wrp + (size_t)ph * 9 * NCOT * 512);
        for (int i = tid; i < NCOT * 9 * 64; i += 256)
            ((int4*)w_lds)[i] = wsrc[i];
        // ---- stage patch half: 4 rows x 130 cols x 4 groups of 16B ----
        const unsigned short* inp = in + (size_t)(b * 2 + ph) * HWSZ * 32;
        for (int idx = tid; idx < 2080; idx += 256) {
            const int G = idx & 3, c = (idx >> 2) % 130, r = idx / 520;
            const int hh = h0 - 1 + r, wc = w0 - 1 + c;
            int4 v = make_int4(0, 0, 0, 0);
            if (hh >= 0 && hh < 512 && wc >= 0 && wc < 512)
                v = *(const int4*)(inp + ((size_t)hh * 512 + wc) * 32 + G * 8);
            *(int4*)(p_lds + ((size_t)(G * 521 + r * 130 + c)) * 16) = v;
        }
        __syncthreads();

        // ---- compute 9 filter slots on this ci-half ----
#pragma unroll
        for (int s = 0; s < 9; ++s) {
            const int dh = s / 3, dwd = s % 3;
            short8 a[2][2];
#pragma unroll
            for (int pr = 0; pr < 2; ++pr)
#pragma unroll
                for (int pb = 0; pb < 2; ++pb)
                    a[pr][pb] = *(const short8*)(p_lds +
                        ((size_t)(lq * 521 + (pr + dh) * 130 + cbase + pb * 16 + dwd)) * 16);
#pragma unroll
            for (int ct = 0; ct < NCOT; ++ct) {
                const short8 bw = *(const short8*)(w_lds + ((size_t)(s * NCOT + ct) * 64 + l) * 8);
#pragma unroll
                for (int pr = 0; pr < 2; ++pr)
#pragma unroll
                    for (int pb = 0; pb < 2; ++pb)
                        acc[pr][pb][ct] = __builtin_amdgcn_mfma_f32_16x16x32_bf16(
                            a[pr][pb], bw, acc[pr][pb][ct], 0, 0, 0);
            }
        }
        __syncthreads();
    }

    float sc[NCOT], bi[NCOT];
#pragma unroll
    for (int ct = 0; ct < NCOT; ++ct) {
        if (BN_) {
            const int co = ct * 16 + lr;
            const float s2 = g[co] * rsqrtf(vr[co] + 1e-5f);
            sc[ct] = s2; bi[ct] = be[co] - mn[co] * s2;
        } else { sc[ct] = 1.f; bi[ct] = 0.f; }
    }

#pragma unroll
    for (int pr = 0; pr < 2; ++pr) {
        const int h = h0 + pr;
#pragma unroll
        for (int pb = 0; pb < 2; ++pb) {
            const int col0 = w0 + wv * 32 + pb * 16 + lq * 4;
#pragma unroll
            for (int ct = 0; ct < NCOT; ++ct) {
                const int co = ct * 16 + lr;
                if (OC == 64 || co < OC) {
#pragma unroll
                    for (int rg = 0; rg < 4; ++rg) {
                        float v = acc[pr][pb][ct][rg];
                        if (BN_) v = v * sc[ct] + bi[ct];
                        if (RELU_) v = fmaxf(v, 0.f);
                        size_t o;
                        if (PLANAR_) {
                            o = (((size_t)(b * OC + co) * 512 + h) * 512) + (col0 + rg);
                        } else {
                            const int half = ct >> 1, colocal = (ct & 1) * 16 + lr;
                            o = ((((size_t)(b * 2 + half) * 512 + h) * 512) + (col0 + rg)) * 32 + colocal;
                        }
                        if (ADD_) v += bf2f(skip[o]);
                        out[o] = f2bf(v);
                    }
                }
            }
        }
    }
}

// ---------------- fused adaptive filter: softmax_v -> vertical taps -> softmax_h -> horizontal ----
// wl: planar30 bf16 [b][30][512][512]; base f32 [b][3][512][512]; out f32 [b][3][512][512]
__global__ __launch_bounds__(256)
void filt_fused_k(const unsigned short* __restrict__ wl, const float* __restrict__ base,
                  float* __restrict__ out)
{
    __shared__ float F[516];

    const int id = blockIdx.x;                      // 3072 blocks
    const int lid = (id & 7) * 384 + (id >> 3);     // XCD chunk swizzle
    const int h = lid & 511;
    const int bc = lid >> 9;                        // b*3 + c
    const int b = bc / 3, c = bc % 3;
    const int t = threadIdx.x;

    if (t < 2) F[t] = 0.f;
    if (t >= 254) F[t + 260] = 0.f;

    const size_t rowoff = (size_t)h * 512;
    const unsigned short* wv_p = wl + ((size_t)(b * 30 + c * 10) * HWSZ) + rowoff;
    const unsigned short* wh_p = wv_p + 5 * HWSZ;
    const float* bp = base + (size_t)bc * HWSZ;

#pragma unroll
    for (int wi = 0; wi < 2; ++wi) {
        const int w = t + wi * 256;
        float v[5]; float mx = -1e30f;
#pragma unroll
        for (int i = 0; i < 5; ++i) { v[i] = bf2f(wv_p[(size_t)i * HWSZ + w]); mx = fmaxf(mx, v[i]); }
        float sm = 0.f;
#pragma unroll
        for (int i = 0; i < 5; ++i) { v[i] = __expf(v[i] - mx); sm += v[i]; }
        const float inv = 1.f / sm;
        float acc = 0.f;
#pragma unroll
        for (int i = 0; i < 5; ++i) {
            const int hh = h + i - 2;
            const float bv = (hh >= 0 && hh < 512) ? bp[(size_t)hh * 512 + w] : 0.f;
            acc = fmaf(bv, v[i] * inv, acc);
        }
        F[w + 2] = acc;
    }
    __syncthreads();

#pragma unroll
    for (int wi = 0; wi < 2; ++wi) {
        const int w = t + wi * 256;
        float v[5]; float mx = -1e30f;
#pragma unroll
        for (int i = 0; i < 5; ++i) { v[i] = bf2f(wh_p[(size_t)i * HWSZ + w]); mx = fmaxf(mx, v[i]); }
        float sm = 0.f;
#pragma unroll
        for (int i = 0; i < 5; ++i) { v[i] = __expf(v[i] - mx); sm += v[i]; }
        const float inv = 1.f / sm;
        float acc = 0.f;
#pragma unroll
        for (int i = 0; i < 5; ++i)
            acc = fmaf(F[w + i], v[i] * inv, acc);
        out[(size_t)bc * HWSZ + rowoff + w] = acc;
    }
}

extern "C" void kernel_launch(void* const* d_in, const int* in_sizes, int n_in,
                              void* d_out, int out_size, void* d_ws, size_t ws_size,
                              hipStream_t stream)
{
    const float* fm      = (const float*)d_in[0];
    const float* base    = (const float*)d_in[1];
    const float* w_first = (const float*)d_in[2];
    const float* kb_w1   = (const float*)d_in[3];
    const float* kb_g1   = (const float*)d_in[4];
    const float* kb_b1   = (const float*)d_in[5];
    const float* kb_m1   = (const float*)d_in[6];
    const float* kb_v1   = (const float*)d_in[7];
    const float* kb_w2   = (const float*)d_in[8];
    const float* kb_g2   = (const float*)d_in[9];
    const float* kb_b2   = (const float*)d_in[10];
    const float* kb_m2   = (const float*)d_in[11];
    const float* kb_v2   = (const float*)d_in[12];
    const float* w_last  = (const float*)d_in[13];

    char* ws = (char*)d_ws;
    unsigned short* wrp3   = (unsigned short*)ws;                 // 8*36864 bf16
    unsigned short* wrpL   = wrp3 + (size_t)8 * 36864;            // 18432 bf16
    unsigned short* wrp7hi = wrpL + 18432;
    unsigned short* wrp7lo = wrp7hi + 26624;
    unsigned short* actA = (unsigned short*)(ws + (1 << 20));     // 67 MB each, split-plane NHWC32
    unsigned short* actB = actA + (size_t)2 * HWSZ * 64;
    unsigned short* actC = actB + (size_t)2 * HWSZ * 64;
    unsigned short* in7hi = actB;                                 // dead until conv7 done
    unsigned short* in7lo = actB + (size_t)2 * HWSZ * 8;
    unsigned short* logits = actC;                                // planar30; actC free by then

    hipFuncSetAttribute((const void*)conv3_mfma<4, 64, true, true, false, false>,
                        hipFuncAttributeMaxDynamicSharedMemorySize, 70208);
    hipFuncSetAttribute((const void*)conv3_mfma<4, 64, true, true, true, false>,
                        hipFuncAttributeMaxDynamicSharedMemorySize, 70208);
    hipFuncSetAttribute((const void*)conv3_mfma<2, 30, false, false, false, true>,
                        hipFuncAttributeMaxDynamicSharedMemorySize, 51776);
    hipFuncSetAttribute((const void*)conv7_mfma,
                        hipFuncAttributeMaxDynamicSharedMemorySize, 34304);

    dim3 blk(256);

    // weight repacks + input prep
    repack3_k<<<dim3(144, 1, 8), blk, 0, stream>>>(kb_w1, kb_w2, wrp3);
    repackL_k<<<dim3(72, 1, 1), blk, 0, stream>>>(w_last, wrpL);
    repack7_k<<<dim3(104, 1, 1), blk, 0, stream>>>(w_first, wrp7hi, wrp7lo);
    prep7_k<<<dim3(2048, 1, 1), blk, 0, stream>>>(fm, in7hi, in7lo);

    // conv_first -> actA
    conv7_mfma<<<dim3(2048, 1, 1), blk, 34304, stream>>>(in7hi, in7lo, wrp7hi, wrp7lo, actA);

    // residual blocks
    unsigned short* cur = actA;
    unsigned short* oth = actC;
    for (int i = 0; i < 4; ++i) {
        conv3_mfma<4, 64, true, true, false, false><<<dim3(2048, 1, 1), blk, 70208, stream>>>(
            cur, wrp3 + (size_t)i * 36864,
            kb_g1 + i * 64, kb_b1 + i * 64, kb_m1 + i * 64, kb_v1 + i * 64,
            nullptr, actB);
        conv3_mfma<4, 64, true, true, true, false><<<dim3(2048, 1, 1), blk, 70208, stream>>>(
            actB, wrp3 + (size_t)(4 + i) * 36864,
            kb_g2 + i * 64, kb_b2 + i * 64, kb_m2 + i * 64, kb_v2 + i * 64,
            cur, oth);
        unsigned short* t = cur; cur = oth; oth = t;
    }

    // conv_last: 64 -> 30, planar30 bf16 logits
    conv3_mfma<2, 30, false, false, false, true><<<dim3(2048, 1, 1), blk, 51776, stream>>>(
        cur, wrpL, nullptr, nullptr, nullptr, nullptr, nullptr, logits);

    // fused adaptive filtering
    filt_fused_k<<<dim3(3072, 1, 1), blk, 0, stream>>>(logits, base, (float*)d_out);
}

// Round 5
// 702.719 us; speedup vs baseline: 10.4896x; 1.2357x over previous
//
#include <hip/hip_runtime.h>
#include <math.h>

typedef __attribute__((ext_vector_type(8)))  short short8;
typedef __attribute__((ext_vector_type(4)))  float float4v;
typedef __attribute__((ext_vector_type(16))) float f32x16;

__device__ __forceinline__ unsigned short f2bf(float f) {
    union { float f; unsigned u; } x; x.f = f;
    unsigned r = x.u + 0x7FFFu + ((x.u >> 16) & 1u);
    return (unsigned short)(r >> 16);
}
__device__ __forceinline__ float bf2f(unsigned short u) {
    union { unsigned u; float f; } x; x.u = ((unsigned)u) << 16;
    return x.f;
}

#define HWSZ ((size_t)512 * 512)

// ---------------- input prep: NCHW f32 (Cin=6) -> NHWC8 bf16 hi + lo planes ----------------
__global__ __launch_bounds__(256)
void prep7_k(const float* __restrict__ in, unsigned short* __restrict__ hi,
             unsigned short* __restrict__ lo)
{
    const int idx = blockIdx.x * 256 + threadIdx.x;   // < 2*512*512
    const int b = idx >> 18, rem = idx & 262143;
    const int h = rem >> 9, w = rem & 511;
    unsigned short vh[8], vl[8];
#pragma unroll
    for (int c = 0; c < 8; ++c) {
        float x = (c < 6) ? in[((size_t)(b * 6 + c)) * HWSZ + (h << 9) + w] : 0.f;
        unsigned short h16 = f2bf(x);
        vh[c] = h16;
        vl[c] = f2bf(x - bf2f(h16));
    }
    const size_t o = ((size_t)idx) * 8;
    *(uint4*)(hi + o) = *(uint4*)vh;
    *(uint4*)(lo + o) = *(uint4*)vl;
}

// ---------------- conv7 weight repack: (64,6,7,7) f32 -> fragment-linear bf16 hi/lo ----------------
__global__ __launch_bounds__(256)
void repack7_k(const float* __restrict__ wsrc, unsigned short* __restrict__ dhi,
               unsigned short* __restrict__ dlo)
{
    const int t = blockIdx.x * 256 + threadIdx.x;   // < 26624
    if (t >= 26624) return;
    const int j = t & 7, l = (t >> 3) & 63, ct = (t >> 9) & 3, kk = t >> 11;
    const int co = ct * 16 + (l & 15);
    const int s = kk * 4 + (l >> 4);
    float v = 0.f;
    if (s < 49 && j < 6)
        v = wsrc[((size_t)(co * 6 + j) * 7 + s / 7) * 7 + s % 7];
    unsigned short h16 = f2bf(v);
    dhi[t] = h16;
    dlo[t] = f2bf(v - bf2f(h16));
}

// ---------------- conv 7x7 MFMA implicit GEMM, split precision, + ReLU ----------------
// out: split-plane NHWC32 bf16  [b][2][512][512][32]
__global__ __launch_bounds__(256)
void conv7_mfma(const unsigned short* __restrict__ inhi,
                const unsigned short* __restrict__ inlo,
                const unsigned short* __restrict__ whi,
                const unsigned short* __restrict__ wlo,
                unsigned short* __restrict__ out)
{
    extern __shared__ char p_lds[];   // [2 planes][8 rows][134 cols][16B]

    const int id = blockIdx.x;                      // 2048 blocks
    const int lid = (id & 7) * 256 + (id >> 3);     // XCD chunk swizzle
    const int w0 = (lid & 3) * 128;
    const int rest = lid >> 2;
    const int h0 = (rest & 255) * 2;
    const int b  = rest >> 8;

    const int tid = threadIdx.x;
    const int wv = tid >> 6, l = tid & 63, lq = l >> 4, lr = l & 15;

    for (int idx = tid; idx < 2144; idx += 256) {   // 2*8*134
        const int plane = idx >= 1072;
        const int rc = plane ? idx - 1072 : idx;
        const int r = rc / 134, c = rc % 134;
        const int hh = h0 - 3 + r, wc = w0 - 3 + c;
        int4 v = make_int4(0, 0, 0, 0);
        if (hh >= 0 && hh < 512 && wc >= 0 && wc < 512) {
            const unsigned short* src = plane ? inlo : inhi;
            v = *(const int4*)(src + ((((size_t)b * 512 + hh) * 512) + wc) * 8);
        }
        *(int4*)(p_lds + (size_t)idx * 16) = v;
    }
    __syncthreads();

    float4v acc[2][2][4];
#pragma unroll
    for (int pr = 0; pr < 2; ++pr)
#pragma unroll
        for (int pb = 0; pb < 2; ++pb)
#pragma unroll
            for (int ct = 0; ct < 4; ++ct)
                acc[pr][pb][ct] = (float4v){0.f, 0.f, 0.f, 0.f};

    const int cbase = wv * 32 + lr;
#pragma unroll
    for (int kk = 0; kk < 13; ++kk) {
        int s = kk * 4 + lq;
        if (s > 48) s = 48;              // padded slots: weights are zero
        const int dh = s / 7, dwd = s % 7;
        short8 ah[2][2], al[2][2];
#pragma unroll
        for (int pr = 0; pr < 2; ++pr)
#pragma unroll
            for (int pb = 0; pb < 2; ++pb) {
                const int off = ((pr + dh) * 134 + cbase + pb * 16 + dwd) * 16;
                ah[pr][pb] = *(const short8*)(p_lds + off);
                al[pr][pb] = *(const short8*)(p_lds + 17152 + off);
            }
#pragma unroll
        for (int ct = 0; ct < 4; ++ct) {
            const short8 bh = *(const short8*)(whi + ((size_t)(kk * 4 + ct) * 64 + l) * 8);
            const short8 bl = *(const short8*)(wlo + ((size_t)(kk * 4 + ct) * 64 + l) * 8);
#pragma unroll
            for (int pr = 0; pr < 2; ++pr)
#pragma unroll
                for (int pb = 0; pb < 2; ++pb) {
                    acc[pr][pb][ct] = __builtin_amdgcn_mfma_f32_16x16x32_bf16(ah[pr][pb], bh, acc[pr][pb][ct], 0, 0, 0);
                    acc[pr][pb][ct] = __builtin_amdgcn_mfma_f32_16x16x32_bf16(al[pr][pb], bh, acc[pr][pb][ct], 0, 0, 0);
                    acc[pr][pb][ct] = __builtin_amdgcn_mfma_f32_16x16x32_bf16(ah[pr][pb], bl, acc[pr][pb][ct], 0, 0, 0);
                }
        }
    }

#pragma unroll
    for (int pr = 0; pr < 2; ++pr) {
        const int h = h0 + pr;
#pragma unroll
        for (int pb = 0; pb < 2; ++pb) {
            const int col0 = w0 + wv * 32 + pb * 16 + lq * 4;
#pragma unroll
            for (int ct = 0; ct < 4; ++ct) {
                const int half = ct >> 1, colocal = (ct & 1) * 16 + lr;
#pragma unroll
                for (int rg = 0; rg < 4; ++rg) {
                    const size_t o = ((((size_t)(b * 2 + half) * 512 + h) * 512) + (col0 + rg)) * 32 + colocal;
                    out[o] = f2bf(fmaxf(acc[pr][pb][ct][rg], 0.f));
                }
            }
        }
    }
}

// ---------------- conv3 weight repack for 32x32x16 path: fold BN scale, fragment-linear ----------------
// layout: [conv][ch][hf][t=s*2+kq][lane][j]   (A-operand: co=ch*32+(l&31), k=(l>>5)*8+j)
__global__ __launch_bounds__(256)
void repack3n_k(const float* __restrict__ w1, const float* __restrict__ w2,
                const float* __restrict__ g1, const float* __restrict__ v1,
                const float* __restrict__ g2, const float* __restrict__ v2,
                unsigned short* __restrict__ dst)
{
    const int conv = blockIdx.z;
    const float* src = (conv < 4) ? (w1 + (size_t)conv * 36864) : (w2 + (size_t)(conv - 4) * 36864);
    const float* g = (conv < 4) ? (g1 + conv * 64) : (g2 + (conv - 4) * 64);
    const float* vv = (conv < 4) ? (v1 + conv * 64) : (v2 + (conv - 4) * 64);
    unsigned short* d = dst + (size_t)conv * 36864;

    const int t = blockIdx.x * 256 + threadIdx.x;   // < 36864
    const int j = t & 7, l = (t >> 3) & 63;
    const int q = t >> 9;            // 0..71
    const int tt = q % 18, m = q / 18;
    const int hf = m & 1, ch = m >> 1;
    const int s = tt >> 1, kq = tt & 1;
    const int co = ch * 32 + (l & 31);
    const int ci = hf * 32 + kq * 16 + (l >> 5) * 8 + j;
    const float sc = g[co] * rsqrtf(vv[co] + 1e-5f);
    d[t] = f2bf(src[((size_t)co * 64 + ci) * 9 + s] * sc);
}

// bias table: bias[conv][co] = beta - mean * scale
__global__ __launch_bounds__(256)
void bias8_k(const float* __restrict__ g1, const float* __restrict__ b1,
             const float* __restrict__ m1, const float* __restrict__ v1,
             const float* __restrict__ g2, const float* __restrict__ b2,
             const float* __restrict__ m2, const float* __restrict__ v2,
             float* __restrict__ bias)
{
    const int t = blockIdx.x * 256 + threadIdx.x;   // < 512
    if (t >= 512) return;
    const int conv = t >> 6, co = t & 63;
    const float* g = (conv < 4) ? (g1 + conv * 64) : (g2 + (conv - 4) * 64);
    const float* be = (conv < 4) ? (b1 + conv * 64) : (b2 + (conv - 4) * 64);
    const float* mn = (conv < 4) ? (m1 + conv * 64) : (m2 + (conv - 4) * 64);
    const float* vv = (conv < 4) ? (v1 + conv * 64) : (v2 + (conv - 4) * 64);
    const float sc = g[co] * rsqrtf(vv[co] + 1e-5f);
    bias[t] = be[co] - mn[co] * sc;
}

// ---------------- conv 3x3 implicit-GEMM, 32x32x16 MFMA, weights-in-registers ----------------
// in/skip/out: split-plane NHWC32 bf16 [b][2][512][512][32]
// block 256 = 4 waves: wave (ch = wv&1 -> co-half, r = wv>>1 -> out row); tile 2 rows x 128 cols
// LDS: pixel patch only, [4 rows][4 kgrp (xor px&3)][132 px] granules of 16B = 33 KB
template <bool ADD_>
__global__ __launch_bounds__(256)
void conv3_mfma32(const unsigned short* __restrict__ in,
                  const unsigned short* __restrict__ wrp,
                  const float* __restrict__ bias,
                  const unsigned short* __restrict__ skip,
                  unsigned short* __restrict__ out)
{
    __shared__ char p_lds[33792];

    const int id = blockIdx.x;                      // 2048 blocks
    const int lid = (id & 7) * 256 + (id >> 3);     // XCD chunk swizzle
    const int w0 = (lid & 3) * 128;
    const int h0 = ((lid >> 2) & 255) * 2;
    const int b  = lid >> 10;

    const int tid = threadIdx.x;
    const int wv = tid >> 6, l = tid & 63;
    const int ch = wv & 1, r = wv >> 1;
    const int lo5 = l & 31, hi = l >> 5;

    f32x16 acc[4];
#pragma unroll
    for (int t4 = 0; t4 < 4; ++t4)
#pragma unroll
        for (int e = 0; e < 16; ++e) acc[t4][e] = 0.f;

    for (int hf = 0; hf < 2; ++hf) {
        if (hf) __syncthreads();     // all waves done reading phase-0 patch

        // ---- stage patch half: 4 rows x 130 px x 4 kgrp (16B each), coalesced global reads ----
        const unsigned short* inp = in + (size_t)(b * 2 + hf) * HWSZ * 32;
        for (int idx = tid; idx < 2080; idx += 256) {
            const int row = idx / 520, rem = idx % 520;
            const int px = rem >> 2, kg = rem & 3;
            const int hh = h0 - 1 + row, wc = w0 - 1 + px;
            int4 v = make_int4(0, 0, 0, 0);
            if (hh >= 0 && hh < 512 && wc >= 0 && wc < 512)
                v = *(const int4*)(inp + ((size_t)hh * 512 + wc) * 32 + kg * 8);
            *(int4*)(p_lds + ((size_t)((row * 4 + (kg ^ (px & 3))) * 132 + px)) * 16) = v;
        }

        // ---- weight A-fragments for this (ch, hf): 18 x 16B per lane, from L2 ----
        short8 wf[18];
        const unsigned short* wp = wrp + (size_t)(ch * 2 + hf) * 18 * 512;
#pragma unroll
        for (int t = 0; t < 18; ++t)
            wf[t] = *(const short8*)(wp + ((size_t)t * 64 + l) * 8);

        __syncthreads();

        // ---- K-loop: 9 filter slots x 2 k-steps; only B (pixels) read from LDS ----
#pragma unroll
        for (int s = 0; s < 9; ++s) {
            const int dh = s / 3, dwd = s % 3;
            const int row = r + dh;
#pragma unroll
            for (int kq = 0; kq < 2; ++kq) {
                const int kg = kq * 2 + hi;
#pragma unroll
                for (int t4 = 0; t4 < 4; ++t4) {
                    const int px = t4 * 32 + dwd + lo5;
                    const short8 pf = *(const short8*)(p_lds +
                        ((size_t)((row * 4 + (kg ^ (px & 3))) * 132 + px)) * 16);
                    acc[t4] = __builtin_amdgcn_mfma_f32_32x32x16_bf16(
                        wf[s * 2 + kq], pf, acc[t4], 0, 0, 0);
                }
            }
        }
    }

    // ---- epilogue: bias (folded BN), ReLU, optional skip-add; D: col=l&31=px, row=co_local ----
    float bv[16];
#pragma unroll
    for (int reg = 0; reg < 16; ++reg)
        bv[reg] = bias[ch * 32 + ((reg & 3) + 8 * (reg >> 2) + 4 * hi)];

    const int h = h0 + r;
    const size_t pbase = ((size_t)(b * 2 + ch) * HWSZ + (size_t)h * 512);
#pragma unroll
    for (int t4 = 0; t4 < 4; ++t4) {
        const size_t o0 = (pbase + (w0 + t4 * 32 + lo5)) * 32;
#pragma unroll
        for (int reg = 0; reg < 16; ++reg) {
            const int colocal = (reg & 3) + 8 * (reg >> 2) + 4 * hi;
            float v = acc[t4][reg] + bv[reg];
            v = fmaxf(v, 0.f);
            if (ADD_) v += bf2f(skip[o0 + colocal]);
            out[o0 + colocal] = f2bf(v);
        }
    }
}

// ---------------- conv_last weight repack (16x16 path, phase-major) ----------------
__global__ __launch_bounds__(256)
void repackL_k(const float* __restrict__ wsrc, unsigned short* __restrict__ d)
{
    const int t = blockIdx.x * 256 + threadIdx.x;   // < 18432
    const int j = t & 7, l = (t >> 3) & 63, ct = (t >> 9) & 1, kks = t >> 10;
    const int hf = kks / 9, s = kks % 9;
    const int co = ct * 16 + (l & 15);
    const int ci = hf * 32 + (l >> 4) * 8 + j;
    d[t] = (co < 30) ? f2bf(wsrc[((size_t)co * 64 + ci) * 9 + s]) : (unsigned short)0;
}

// ---------------- conv_last: 16x16 MFMA ci-split 2-phase (as round 4) ----------------
template <int NCOT, int OC>
__global__ __launch_bounds__(256)
void conv3_last(const unsigned short* __restrict__ in,
                const unsigned short* __restrict__ wrp,
                unsigned short* __restrict__ out)
{
    extern __shared__ char smem[];
    unsigned short* w_lds = (unsigned short*)smem;            // NCOT*9*1024 B per phase
    char* p_lds = smem + NCOT * 9 * 1024;                     // 4 planes x 521 granules x 16 B

    const int id = blockIdx.x;                      // 2048 blocks
    const int lid = (id & 7) * 256 + (id >> 3);
    const int w0 = (lid & 3) * 128;
    const int rest = lid >> 2;
    const int h0 = (rest & 255) * 2;
    const int b  = rest >> 8;

    const int tid = threadIdx.x;
    const int wv = tid >> 6, l = tid & 63, lq = l >> 4, lr = l & 15;
    const int cbase = wv * 32 + lr;

    float4v acc[2][2][NCOT];
#pragma unroll
    for (int pr = 0; pr < 2; ++pr)
#pragma unroll
        for (int pb = 0; pb < 2; ++pb)
#pragma unroll
            for (int ct = 0; ct < NCOT; ++ct)
                acc[pr][pb][ct] = (float4v){0.f, 0.f, 0.f, 0.f};

    for (int ph = 0; ph < 2; ++ph) {
        const int4* wsrc = (const int4*)(wrp + (size_t)ph * 9 * NCOT * 512);
        for (int i = tid; i < NCOT * 9 * 64; i += 256)
            ((int4*)w_lds)[i] = wsrc[i];
        const unsigned short* inp = in + (size_t)(b * 2 + ph) * HWSZ * 32;
        for (int idx = tid; idx < 2080; idx += 256) {
            const int G = idx & 3, c = (idx >> 2) % 130, rr = idx / 520;
            const int hh = h0 - 1 + rr, wc = w0 - 1 + c;
            int4 v = make_int4(0, 0, 0, 0);
            if (hh >= 0 && hh < 512 && wc >= 0 && wc < 512)
                v = *(const int4*)(inp + ((size_t)hh * 512 + wc) * 32 + G * 8);
            *(int4*)(p_lds + ((size_t)(G * 521 + rr * 130 + c)) * 16) = v;
        }
        __syncthreads();

#pragma unroll
        for (int s = 0; s < 9; ++s) {
            const int dh = s / 3, dwd = s % 3;
            short8 a[2][2];
#pragma unroll
            for (int pr = 0; pr < 2; ++pr)
#pragma unroll
                for (int pb = 0; pb < 2; ++pb)
                    a[pr][pb] = *(const short8*)(p_lds +
                        ((size_t)(lq * 521 + (pr + dh) * 130 + cbase + pb * 16 + dwd)) * 16);
#pragma unroll
            for (int ct = 0; ct < NCOT; ++ct) {
                const short8 bw = *(const short8*)(w_lds + ((size_t)(s * NCOT + ct) * 64 + l) * 8);
#pragma unroll
                for (int pr = 0; pr < 2; ++pr)
#pragma unroll
                    for (int pb = 0; pb < 2; ++pb)
                        acc[pr][pb][ct] = __builtin_amdgcn_mfma_f32_16x16x32_bf16(
                            a[pr][pb], bw, acc[pr][pb][ct], 0, 0, 0);
            }
        }
        __syncthreads();
    }

#pragma unroll
    for (int pr = 0; pr < 2; ++pr) {
        const int h = h0 + pr;
#pragma unroll
        for (int pb = 0; pb < 2; ++pb) {
            const int col0 = w0 + wv * 32 + pb * 16 + lq * 4;
#pragma unroll
            for (int ct = 0; ct < NCOT; ++ct) {
                const int co = ct * 16 + lr;
                if (co < OC) {
#pragma unroll
                    for (int rg = 0; rg < 4; ++rg) {
                        const size_t o = (((size_t)(b * OC + co) * 512 + h) * 512) + (col0 + rg);
                        out[o] = f2bf(acc[pr][pb][ct][rg]);
                    }
                }
            }
        }
    }
}

// ---------------- fused adaptive filter ----------------
__global__ __launch_bounds__(256)
void filt_fused_k(const unsigned short* __restrict__ wl, const float* __restrict__ base,
                  float* __restrict__ out)
{
    __shared__ float F[516];

    const int id = blockIdx.x;                      // 3072 blocks
    const int lid = (id & 7) * 384 + (id >> 3);
    const int h = lid & 511;
    const int bc = lid >> 9;
    const int b = bc / 3, c = bc % 3;
    const int t = threadIdx.x;

    if (t < 2) F[t] = 0.f;
    if (t >= 254) F[t + 260] = 0.f;

    const size_t rowoff = (size_t)h * 512;
    const unsigned short* wv_p = wl + ((size_t)(b * 30 + c * 10) * HWSZ) + rowoff;
    const unsigned short* wh_p = wv_p + 5 * HWSZ;
    const float* bp = base + (size_t)bc * HWSZ;

#pragma unroll
    for (int wi = 0; wi < 2; ++wi) {
        const int w = t + wi * 256;
        float v[5]; float mx = -1e30f;
#pragma unroll
        for (int i = 0; i < 5; ++i) { v[i] = bf2f(wv_p[(size_t)i * HWSZ + w]); mx = fmaxf(mx, v[i]); }
        float sm = 0.f;
#pragma unroll
        for (int i = 0; i < 5; ++i) { v[i] = __expf(v[i] - mx); sm += v[i]; }
        const float inv = 1.f / sm;
        float acc = 0.f;
#pragma unroll
        for (int i = 0; i < 5; ++i) {
            const int hh = h + i - 2;
            const float bvv = (hh >= 0 && hh < 512) ? bp[(size_t)hh * 512 + w] : 0.f;
            acc = fmaf(bvv, v[i] * inv, acc);
        }
        F[w + 2] = acc;
    }
    __syncthreads();

#pragma unroll
    for (int wi = 0; wi < 2; ++wi) {
        const int w = t + wi * 256;
        float v[5]; float mx = -1e30f;
#pragma unroll
        for (int i = 0; i < 5; ++i) { v[i] = bf2f(wh_p[(size_t)i * HWSZ + w]); mx = fmaxf(mx, v[i]); }
        float sm = 0.f;
#pragma unroll
        for (int i = 0; i < 5; ++i) { v[i] = __expf(v[i] - mx); sm += v[i]; }
        const float inv = 1.f / sm;
        float acc = 0.f;
#pragma unroll
        for (int i = 0; i < 5; ++i)
            acc = fmaf(F[w + i], v[i] * inv, acc);
        out[(size_t)bc * HWSZ + rowoff + w] = acc;
    }
}

extern "C" void kernel_launch(void* const* d_in, const int* in_sizes, int n_in,
                              void* d_out, int out_size, void* d_ws, size_t ws_size,
                              hipStream_t stream)
{
    const float* fm      = (const float*)d_in[0];
    const float* base    = (const float*)d_in[1];
    const float* w_first = (const float*)d_in[2];
    const float* kb_w1   = (const float*)d_in[3];
    const float* kb_g1   = (const float*)d_in[4];
    const float* kb_b1   = (const float*)d_in[5];
    const float* kb_m1   = (const float*)d_in[6];
    const float* kb_v1   = (const float*)d_in[7];
    const float* kb_w2   = (const float*)d_in[8];
    const float* kb_g2   = (const float*)d_in[9];
    const float* kb_b2   = (const float*)d_in[10];
    const float* kb_m2   = (const float*)d_in[11];
    const float* kb_v2   = (const float*)d_in[12];
    const float* w_last  = (const float*)d_in[13];

    char* ws = (char*)d_ws;
    unsigned short* wrp3n  = (unsigned short*)ws;                 // 8*36864 bf16 = 589824 B
    unsigned short* wrpL   = wrp3n + (size_t)8 * 36864;           // 36864 B
    unsigned short* wrp7hi = wrpL + 18432;                        // 53248 B
    unsigned short* wrp7lo = wrp7hi + 26624;                      // 53248 B
    float*          biasws = (float*)(wrp7lo + 26624);            // 2048 B
    unsigned short* actA = (unsigned short*)(ws + (1 << 20));     // 67 MB each, split-plane NHWC32
    unsigned short* actB = actA + (size_t)2 * HWSZ * 64;
    unsigned short* actC = actB + (size_t)2 * HWSZ * 64;
    unsigned short* in7hi = actB;                                 // dead once conv7 done
    unsigned short* in7lo = actB + (size_t)2 * HWSZ * 8;
    unsigned short* logits = actC;                                // planar30; actC free by then

    hipFuncSetAttribute((const void*)conv3_last<2, 30>,
                        hipFuncAttributeMaxDynamicSharedMemorySize, 51776);
    hipFuncSetAttribute((const void*)conv7_mfma,
                        hipFuncAttributeMaxDynamicSharedMemorySize, 34304);

    dim3 blk(256);

    // weight repacks + input prep
    repack3n_k<<<dim3(144, 1, 8), blk, 0, stream>>>(kb_w1, kb_w2, kb_g1, kb_v1, kb_g2, kb_v2, wrp3n);
    bias8_k<<<dim3(2, 1, 1), blk, 0, stream>>>(kb_g1, kb_b1, kb_m1, kb_v1, kb_g2, kb_b2, kb_m2, kb_v2, biasws);
    repackL_k<<<dim3(72, 1, 1), blk, 0, stream>>>(w_last, wrpL);
    repack7_k<<<dim3(104, 1, 1), blk, 0, stream>>>(w_first, wrp7hi, wrp7lo);
    prep7_k<<<dim3(2048, 1, 1), blk, 0, stream>>>(fm, in7hi, in7lo);

    // conv_first -> actA
    conv7_mfma<<<dim3(2048, 1, 1), blk, 34304, stream>>>(in7hi, in7lo, wrp7hi, wrp7lo, actA);

    // residual blocks (32x32x16, weights-in-registers)
    unsigned short* cur = actA;
    unsigned short* oth = actC;
    for (int i = 0; i < 4; ++i) {
        conv3_mfma32<false><<<dim3(2048, 1, 1), blk, 0, stream>>>(
            cur, wrp3n + (size_t)i * 36864, biasws + i * 64, nullptr, actB);
        conv3_mfma32<true><<<dim3(2048, 1, 1), blk, 0, stream>>>(
            actB, wrp3n + (size_t)(4 + i) * 36864, biasws + (4 + i) * 64, cur, oth);
        unsigned short* t = cur; cur = oth; oth = t;
    }

    // conv_last: 64 -> 30, planar30 bf16 logits
    conv3_last<2, 30><<<dim3(2048, 1, 1), blk, 51776, stream>>>(cur, wrpL, logits);

    // fused adaptive filtering
    filt_fused_k<<<dim3(3072, 1, 1), blk, 0, stream>>>(logits, base, (float*)d_out);
}

// Round 6
// 674.960 us; speedup vs baseline: 10.9210x; 1.0411x over previous
//
#include <hip/hip_runtime.h>
#include <math.h>

typedef __attribute__((ext_vector_type(8)))  short short8;
typedef __attribute__((ext_vector_type(4)))  float float4v;
typedef __attribute__((ext_vector_type(16))) float f32x16;

__device__ __forceinline__ unsigned short f2bf(float f) {
    union { float f; unsigned u; } x; x.f = f;
    unsigned r = x.u + 0x7FFFu + ((x.u >> 16) & 1u);
    return (unsigned short)(r >> 16);
}
__device__ __forceinline__ float bf2f(unsigned short u) {
    union { unsigned u; float f; } x; x.u = ((unsigned)u) << 16;
    return x.f;
}

#define HWSZ ((size_t)512 * 512)

// ---------------- input prep: NCHW f32 (Cin=6) -> NHWC8 bf16 hi + lo planes ----------------
__global__ __launch_bounds__(256)
void prep7_k(const float* __restrict__ in, unsigned short* __restrict__ hi,
             unsigned short* __restrict__ lo)
{
    const int idx = blockIdx.x * 256 + threadIdx.x;   // < 2*512*512
    const int b = idx >> 18, rem = idx & 262143;
    const int h = rem >> 9, w = rem & 511;
    unsigned short vh[8], vl[8];
#pragma unroll
    for (int c = 0; c < 8; ++c) {
        float x = (c < 6) ? in[((size_t)(b * 6 + c)) * HWSZ + (h << 9) + w] : 0.f;
        unsigned short h16 = f2bf(x);
        vh[c] = h16;
        vl[c] = f2bf(x - bf2f(h16));
    }
    const size_t o = ((size_t)idx) * 8;
    *(uint4*)(hi + o) = *(uint4*)vh;
    *(uint4*)(lo + o) = *(uint4*)vl;
}

// ---------------- conv7 weight repack: (64,6,7,7) f32 -> fragment-linear bf16 hi/lo ----------------
__global__ __launch_bounds__(256)
void repack7_k(const float* __restrict__ wsrc, unsigned short* __restrict__ dhi,
               unsigned short* __restrict__ dlo)
{
    const int t = blockIdx.x * 256 + threadIdx.x;   // < 26624
    if (t >= 26624) return;
    const int j = t & 7, l = (t >> 3) & 63, ct = (t >> 9) & 3, kk = t >> 11;
    const int co = ct * 16 + (l & 15);
    const int s = kk * 4 + (l >> 4);
    float v = 0.f;
    if (s < 49 && j < 6)
        v = wsrc[((size_t)(co * 6 + j) * 7 + s / 7) * 7 + s % 7];
    unsigned short h16 = f2bf(v);
    dhi[t] = h16;
    dlo[t] = f2bf(v - bf2f(h16));
}

// ---------------- conv 7x7 MFMA implicit GEMM, split precision, + ReLU ----------------
// out: split-plane NHWC32 bf16  [b][2][512][512][32]
__global__ __launch_bounds__(256)
void conv7_mfma(const unsigned short* __restrict__ inhi,
                const unsigned short* __restrict__ inlo,
                const unsigned short* __restrict__ whi,
                const unsigned short* __restrict__ wlo,
                unsigned short* __restrict__ out)
{
    extern __shared__ char p_lds[];   // [2 planes][8 rows][134 cols][16B]

    const int id = blockIdx.x;                      // 2048 blocks
    const int lid = (id & 7) * 256 + (id >> 3);     // XCD chunk swizzle
    const int w0 = (lid & 3) * 128;
    const int rest = lid >> 2;
    const int h0 = (rest & 255) * 2;
    const int b  = rest >> 8;

    const int tid = threadIdx.x;
    const int wv = tid >> 6, l = tid & 63, lq = l >> 4, lr = l & 15;

    for (int idx = tid; idx < 2144; idx += 256) {   // 2*8*134
        const int plane = idx >= 1072;
        const int rc = plane ? idx - 1072 : idx;
        const int r = rc / 134, c = rc % 134;
        const int hh = h0 - 3 + r, wc = w0 - 3 + c;
        int4 v = make_int4(0, 0, 0, 0);
        if (hh >= 0 && hh < 512 && wc >= 0 && wc < 512) {
            const unsigned short* src = plane ? inlo : inhi;
            v = *(const int4*)(src + ((((size_t)b * 512 + hh) * 512) + wc) * 8);
        }
        *(int4*)(p_lds + (size_t)idx * 16) = v;
    }
    __syncthreads();

    float4v acc[2][2][4];
#pragma unroll
    for (int pr = 0; pr < 2; ++pr)
#pragma unroll
        for (int pb = 0; pb < 2; ++pb)
#pragma unroll
            for (int ct = 0; ct < 4; ++ct)
                acc[pr][pb][ct] = (float4v){0.f, 0.f, 0.f, 0.f};

    const int cbase = wv * 32 + lr;
#pragma unroll
    for (int kk = 0; kk < 13; ++kk) {
        int s = kk * 4 + lq;
        if (s > 48) s = 48;              // padded slots: weights are zero
        const int dh = s / 7, dwd = s % 7;
        short8 ah[2][2], al[2][2];
#pragma unroll
        for (int pr = 0; pr < 2; ++pr)
#pragma unroll
            for (int pb = 0; pb < 2; ++pb) {
                const int off = ((pr + dh) * 134 + cbase + pb * 16 + dwd) * 16;
                ah[pr][pb] = *(const short8*)(p_lds + off);
                al[pr][pb] = *(const short8*)(p_lds + 17152 + off);
            }
#pragma unroll
        for (int ct = 0; ct < 4; ++ct) {
            const short8 bh = *(const short8*)(whi + ((size_t)(kk * 4 + ct) * 64 + l) * 8);
            const short8 bl = *(const short8*)(wlo + ((size_t)(kk * 4 + ct) * 64 + l) * 8);
#pragma unroll
            for (int pr = 0; pr < 2; ++pr)
#pragma unroll
                for (int pb = 0; pb < 2; ++pb) {
                    acc[pr][pb][ct] = __builtin_amdgcn_mfma_f32_16x16x32_bf16(ah[pr][pb], bh, acc[pr][pb][ct], 0, 0, 0);
                    acc[pr][pb][ct] = __builtin_amdgcn_mfma_f32_16x16x32_bf16(al[pr][pb], bh, acc[pr][pb][ct], 0, 0, 0);
                    acc[pr][pb][ct] = __builtin_amdgcn_mfma_f32_16x16x32_bf16(ah[pr][pb], bl, acc[pr][pb][ct], 0, 0, 0);
                }
        }
    }

#pragma unroll
    for (int pr = 0; pr < 2; ++pr) {
        const int h = h0 + pr;
#pragma unroll
        for (int pb = 0; pb < 2; ++pb) {
            const int col0 = w0 + wv * 32 + pb * 16 + lq * 4;
#pragma unroll
            for (int ct = 0; ct < 4; ++ct) {
                const int half = ct >> 1, colocal = (ct & 1) * 16 + lr;
#pragma unroll
                for (int rg = 0; rg < 4; ++rg) {
                    const size_t o = ((((size_t)(b * 2 + half) * 512 + h) * 512) + (col0 + rg)) * 32 + colocal;
                    out[o] = f2bf(fmaxf(acc[pr][pb][ct][rg], 0.f));
                }
            }
        }
    }
}

// ---------------- conv3 weight repack for 32x32x16 path: fold BN scale, fragment-linear ----------------
// layout: [conv][ch][hf][t=s*2+kq][lane][j]   (B-operand: co=ch*32+(l&31), k=(l>>5)*8+j)
__global__ __launch_bounds__(256)
void repack3n_k(const float* __restrict__ w1, const float* __restrict__ w2,
                const float* __restrict__ g1, const float* __restrict__ v1,
                const float* __restrict__ g2, const float* __restrict__ v2,
                unsigned short* __restrict__ dst)
{
    const int conv = blockIdx.z;
    const float* src = (conv < 4) ? (w1 + (size_t)conv * 36864) : (w2 + (size_t)(conv - 4) * 36864);
    const float* g = (conv < 4) ? (g1 + conv * 64) : (g2 + (conv - 4) * 64);
    const float* vv = (conv < 4) ? (v1 + conv * 64) : (v2 + (conv - 4) * 64);
    unsigned short* d = dst + (size_t)conv * 36864;

    const int t = blockIdx.x * 256 + threadIdx.x;   // < 36864
    const int j = t & 7, l = (t >> 3) & 63;
    const int q = t >> 9;            // 0..71
    const int tt = q % 18, m = q / 18;
    const int hf = m & 1, ch = m >> 1;
    const int s = tt >> 1, kq = tt & 1;
    const int co = ch * 32 + (l & 31);
    const int ci = hf * 32 + kq * 16 + (l >> 5) * 8 + j;
    const float sc = g[co] * rsqrtf(vv[co] + 1e-5f);
    d[t] = f2bf(src[((size_t)co * 64 + ci) * 9 + s] * sc);
}

// bias table: bias[conv][co] = beta - mean * scale
__global__ __launch_bounds__(256)
void bias8_k(const float* __restrict__ g1, const float* __restrict__ b1,
             const float* __restrict__ m1, const float* __restrict__ v1,
             const float* __restrict__ g2, const float* __restrict__ b2,
             const float* __restrict__ m2, const float* __restrict__ v2,
             float* __restrict__ bias)
{
    const int t = blockIdx.x * 256 + threadIdx.x;   // < 512
    if (t >= 512) return;
    const int conv = t >> 6, co = t & 63;
    const float* g = (conv < 4) ? (g1 + conv * 64) : (g2 + (conv - 4) * 64);
    const float* be = (conv < 4) ? (b1 + conv * 64) : (b2 + (conv - 4) * 64);
    const float* mn = (conv < 4) ? (m1 + conv * 64) : (m2 + (conv - 4) * 64);
    const float* vv = (conv < 4) ? (v1 + conv * 64) : (v2 + (conv - 4) * 64);
    const float sc = g[co] * rsqrtf(vv[co] + 1e-5f);
    bias[t] = be[co] - mn[co] * sc;
}

// ---------------- conv 3x3 implicit-GEMM, 32x32x16 MFMA, A=pixels B=weights(regs) ----------------
// in/skip/out: split-plane NHWC32 bf16 [b][2][512][512][32]
// block 512 = 8 waves: (ch = wv&1 -> co-half, r = wv>>1 -> out row 0..3); tile 4 rows x 128 px
// LDS: pixel patch only, [6 rows][4 kgrp (xor px&3)][132 px] granules of 16B = 50.7 KB
// D layout col=l&31=co_local -> stores/skip-reads are 64B-contiguous per 32 lanes (no RMW)
template <bool ADD_>
__global__ __launch_bounds__(512)
void conv3_mfma32(const unsigned short* __restrict__ in,
                  const unsigned short* __restrict__ wrp,
                  const float* __restrict__ bias,
                  const unsigned short* __restrict__ skip,
                  unsigned short* __restrict__ out)
{
    __shared__ char p_lds[50688];

    const int id = blockIdx.x;                      // 1024 blocks
    const int lid = (id & 7) * 128 + (id >> 3);     // XCD chunk swizzle
    const int w0 = (lid & 3) * 128;
    const int h0 = ((lid >> 2) & 127) * 4;
    const int b  = lid >> 9;

    const int tid = threadIdx.x;
    const int wv = tid >> 6, l = tid & 63;
    const int ch = wv & 1, r = wv >> 1;
    const int lo5 = l & 31, hi = l >> 5;

    f32x16 acc[4];
#pragma unroll
    for (int t4 = 0; t4 < 4; ++t4)
#pragma unroll
        for (int e = 0; e < 16; ++e) acc[t4][e] = 0.f;

    for (int hf = 0; hf < 2; ++hf) {
        if (hf) __syncthreads();     // all waves done reading phase-0 patch

        // ---- stage patch half: 6 rows x 130 px x 4 kgrp (16B each), coalesced global reads ----
        const unsigned short* inp = in + (size_t)(b * 2 + hf) * HWSZ * 32;
        for (int idx = tid; idx < 3120; idx += 512) {
            const int row = idx / 520, rem = idx % 520;
            const int px = rem >> 2, kg = rem & 3;
            const int hh = h0 - 1 + row, wc = w0 - 1 + px;
            int4 v = make_int4(0, 0, 0, 0);
            if (hh >= 0 && hh < 512 && wc >= 0 && wc < 512)
                v = *(const int4*)(inp + ((size_t)hh * 512 + wc) * 32 + kg * 8);
            *(int4*)(p_lds + ((size_t)((row * 4 + (kg ^ (px & 3))) * 132 + px)) * 16) = v;
        }

        // ---- weight B-fragments for this (ch, hf): 18 x 16B per lane, from L2 ----
        short8 wf[18];
        const unsigned short* wp = wrp + (size_t)(ch * 2 + hf) * 18 * 512;
#pragma unroll
        for (int t = 0; t < 18; ++t)
            wf[t] = *(const short8*)(wp + ((size_t)t * 64 + l) * 8);

        __syncthreads();

        // ---- K-loop: 9 filter slots x 2 k-steps; only A (pixels) read from LDS ----
#pragma unroll
        for (int s = 0; s < 9; ++s) {
            const int dh = s / 3, dwd = s % 3;
            const int row = r + dh;
#pragma unroll
            for (int kq = 0; kq < 2; ++kq) {
                const int kg = kq * 2 + hi;
#pragma unroll
                for (int t4 = 0; t4 < 4; ++t4) {
                    const int px = t4 * 32 + dwd + lo5;
                    const short8 pf = *(const short8*)(p_lds +
                        ((size_t)((row * 4 + (kg ^ (px & 3))) * 132 + px)) * 16);
                    acc[t4] = __builtin_amdgcn_mfma_f32_32x32x16_bf16(
                        pf, wf[s * 2 + kq], acc[t4], 0, 0, 0);
                }
            }
        }
    }

    // ---- epilogue: D col = l&31 = co_local, row index = px offset; coalesced 2B stores ----
    const float bvs = bias[ch * 32 + lo5];
    const int h = h0 + r;
    const size_t pbase = ((size_t)(b * 2 + ch) * HWSZ + (size_t)h * 512);
#pragma unroll
    for (int t4 = 0; t4 < 4; ++t4) {
#pragma unroll
        for (int reg = 0; reg < 16; ++reg) {
            const int pxl = t4 * 32 + (reg & 3) + 8 * (reg >> 2) + 4 * hi;
            const size_t o = (pbase + (w0 + pxl)) * 32 + lo5;
            float v = fmaxf(acc[t4][reg] + bvs, 0.f);
            if (ADD_) v += bf2f(skip[o]);
            out[o] = f2bf(v);
        }
    }
}

// ---------------- conv_last weight repack (16x16 path, phase-major) ----------------
__global__ __launch_bounds__(256)
void repackL_k(const float* __restrict__ wsrc, unsigned short* __restrict__ d)
{
    const int t = blockIdx.x * 256 + threadIdx.x;   // < 18432
    const int j = t & 7, l = (t >> 3) & 63, ct = (t >> 9) & 1, kks = t >> 10;
    const int hf = kks / 9, s = kks % 9;
    const int co = ct * 16 + (l & 15);
    const int ci = hf * 32 + (l >> 4) * 8 + j;
    d[t] = (co < 30) ? f2bf(wsrc[((size_t)co * 64 + ci) * 9 + s]) : (unsigned short)0;
}

// ---------------- conv_last: 16x16 MFMA ci-split 2-phase ----------------
template <int NCOT, int OC>
__global__ __launch_bounds__(256)
void conv3_last(const unsigned short* __restrict__ in,
                const unsigned short* __restrict__ wrp,
                unsigned short* __restrict__ out)
{
    extern __shared__ char smem[];
    unsigned short* w_lds = (unsigned short*)smem;            // NCOT*9*1024 B per phase
    char* p_lds = smem + NCOT * 9 * 1024;                     // 4 planes x 521 granules x 16 B

    const int id = blockIdx.x;                      // 2048 blocks
    const int lid = (id & 7) * 256 + (id >> 3);
    const int w0 = (lid & 3) * 128;
    const int rest = lid >> 2;
    const int h0 = (rest & 255) * 2;
    const int b  = rest >> 8;

    const int tid = threadIdx.x;
    const int wv = tid >> 6, l = tid & 63, lq = l >> 4, lr = l & 15;
    const int cbase = wv * 32 + lr;

    float4v acc[2][2][NCOT];
#pragma unroll
    for (int pr = 0; pr < 2; ++pr)
#pragma unroll
        for (int pb = 0; pb < 2; ++pb)
#pragma unroll
            for (int ct = 0; ct < NCOT; ++ct)
                acc[pr][pb][ct] = (float4v){0.f, 0.f, 0.f, 0.f};

    for (int ph = 0; ph < 2; ++ph) {
        const int4* wsrc = (const int4*)(wrp + (size_t)ph * 9 * NCOT * 512);
        for (int i = tid; i < NCOT * 9 * 64; i += 256)
            ((int4*)w_lds)[i] = wsrc[i];
        const unsigned short* inp = in + (size_t)(b * 2 + ph) * HWSZ * 32;
        for (int idx = tid; idx < 2080; idx += 256) {
            const int G = idx & 3, c = (idx >> 2) % 130, rr = idx / 520;
            const int hh = h0 - 1 + rr, wc = w0 - 1 + c;
            int4 v = make_int4(0, 0, 0, 0);
            if (hh >= 0 && hh < 512 && wc >= 0 && wc < 512)
                v = *(const int4*)(inp + ((size_t)hh * 512 + wc) * 32 + G * 8);
            *(int4*)(p_lds + ((size_t)(G * 521 + rr * 130 + c)) * 16) = v;
        }
        __syncthreads();

#pragma unroll
        for (int s = 0; s < 9; ++s) {
            const int dh = s / 3, dwd = s % 3;
            short8 a[2][2];
#pragma unroll
            for (int pr = 0; pr < 2; ++pr)
#pragma unroll
                for (int pb = 0; pb < 2; ++pb)
                    a[pr][pb] = *(const short8*)(p_lds +
                        ((size_t)(lq * 521 + (pr + dh) * 130 + cbase + pb * 16 + dwd)) * 16);
#pragma unroll
            for (int ct = 0; ct < NCOT; ++ct) {
                const short8 bw = *(const short8*)(w_lds + ((size_t)(s * NCOT + ct) * 64 + l) * 8);
#pragma unroll
                for (int pr = 0; pr < 2; ++pr)
#pragma unroll
                    for (int pb = 0; pb < 2; ++pb)
                        acc[pr][pb][ct] = __builtin_amdgcn_mfma_f32_16x16x32_bf16(
                            a[pr][pb], bw, acc[pr][pb][ct], 0, 0, 0);
            }
        }
        __syncthreads();
    }

#pragma unroll
    for (int pr = 0; pr < 2; ++pr) {
        const int h = h0 + pr;
#pragma unroll
        for (int pb = 0; pb < 2; ++pb) {
            const int col0 = w0 + wv * 32 + pb * 16 + lq * 4;
#pragma unroll
            for (int ct = 0; ct < NCOT; ++ct) {
                const int co = ct * 16 + lr;
                if (co < OC) {
#pragma unroll
                    for (int rg = 0; rg < 4; ++rg) {
                        const size_t o = (((size_t)(b * OC + co) * 512 + h) * 512) + (col0 + rg);
                        out[o] = f2bf(acc[pr][pb][ct][rg]);
                    }
                }
            }
        }
    }
}

// ---------------- fused adaptive filter ----------------
__global__ __launch_bounds__(256)
void filt_fused_k(const unsigned short* __restrict__ wl, const float* __restrict__ base,
                  float* __restrict__ out)
{
    __shared__ float F[516];

    const int id = blockIdx.x;                      // 3072 blocks
    const int lid = (id & 7) * 384 + (id >> 3);
    const int h = lid & 511;
    const int bc = lid >> 9;
    const int b = bc / 3, c = bc % 3;
    const int t = threadIdx.x;

    if (t < 2) F[t] = 0.f;
    if (t >= 254) F[t + 260] = 0.f;

    const size_t rowoff = (size_t)h * 512;
    const unsigned short* wv_p = wl + ((size_t)(b * 30 + c * 10) * HWSZ) + rowoff;
    const unsigned short* wh_p = wv_p + 5 * HWSZ;
    const float* bp = base + (size_t)bc * HWSZ;

#pragma unroll
    for (int wi = 0; wi < 2; ++wi) {
        const int w = t + wi * 256;
        float v[5]; float mx = -1e30f;
#pragma unroll
        for (int i = 0; i < 5; ++i) { v[i] = bf2f(wv_p[(size_t)i * HWSZ + w]); mx = fmaxf(mx, v[i]); }
        float sm = 0.f;
#pragma unroll
        for (int i = 0; i < 5; ++i) { v[i] = __expf(v[i] - mx); sm += v[i]; }
        const float inv = 1.f / sm;
        float acc = 0.f;
#pragma unroll
        for (int i = 0; i < 5; ++i) {
            const int hh = h + i - 2;
            const float bvv = (hh >= 0 && hh < 512) ? bp[(size_t)hh * 512 + w] : 0.f;
            acc = fmaf(bvv, v[i] * inv, acc);
        }
        F[w + 2] = acc;
    }
    __syncthreads();

#pragma unroll
    for (int wi = 0; wi < 2; ++wi) {
        const int w = t + wi * 256;
        float v[5]; float mx = -1e30f;
#pragma unroll
        for (int i = 0; i < 5; ++i) { v[i] = bf2f(wh_p[(size_t)i * HWSZ + w]); mx = fmaxf(mx, v[i]); }
        float sm = 0.f;
#pragma unroll
        for (int i = 0; i < 5; ++i) { v[i] = __expf(v[i] - mx); sm += v[i]; }
        const float inv = 1.f / sm;
        float acc = 0.f;
#pragma unroll
        for (int i = 0; i < 5; ++i)
            acc = fmaf(F[w + i], v[i] * inv, acc);
        out[(size_t)bc * HWSZ + rowoff + w] = acc;
    }
}

extern "C" void kernel_launch(void* const* d_in, const int* in_sizes, int n_in,
                              void* d_out, int out_size, void* d_ws, size_t ws_size,
                              hipStream_t stream)
{
    const float* fm      = (const float*)d_in[0];
    const float* base    = (const float*)d_in[1];
    const float* w_first = (const float*)d_in[2];
    const float* kb_w1   = (const float*)d_in[3];
    const float* kb_g1   = (const float*)d_in[4];
    const float* kb_b1   = (const float*)d_in[5];
    const float* kb_m1   = (const float*)d_in[6];
    const float* kb_v1   = (const float*)d_in[7];
    const float* kb_w2   = (const float*)d_in[8];
    const float* kb_g2   = (const float*)d_in[9];
    const float* kb_b2   = (const float*)d_in[10];
    const float* kb_m2   = (const float*)d_in[11];
    const float* kb_v2   = (const float*)d_in[12];
    const float* w_last  = (const float*)d_in[13];

    char* ws = (char*)d_ws;
    unsigned short* wrp3n  = (unsigned short*)ws;                 // 8*36864 bf16 = 589824 B
    unsigned short* wrpL   = wrp3n + (size_t)8 * 36864;           // 36864 B
    unsigned short* wrp7hi = wrpL + 18432;                        // 53248 B
    unsigned short* wrp7lo = wrp7hi + 26624;                      // 53248 B
    float*          biasws = (float*)(wrp7lo + 26624);            // 2048 B
    unsigned short* actA = (unsigned short*)(ws + (1 << 20));     // 67 MB each, split-plane NHWC32
    unsigned short* actB = actA + (size_t)2 * HWSZ * 64;
    unsigned short* actC = actB + (size_t)2 * HWSZ * 64;
    unsigned short* in7hi = actB;                                 // dead once conv7 done
    unsigned short* in7lo = actB + (size_t)2 * HWSZ * 8;
    unsigned short* logits = actC;                                // planar30; actC free by then

    hipFuncSetAttribute((const void*)conv3_last<2, 30>,
                        hipFuncAttributeMaxDynamicSharedMemorySize, 51776);
    hipFuncSetAttribute((const void*)conv7_mfma,
                        hipFuncAttributeMaxDynamicSharedMemorySize, 34304);

    dim3 blk(256);

    // weight repacks + input prep
    repack3n_k<<<dim3(144, 1, 8), blk, 0, stream>>>(kb_w1, kb_w2, kb_g1, kb_v1, kb_g2, kb_v2, wrp3n);
    bias8_k<<<dim3(2, 1, 1), blk, 0, stream>>>(kb_g1, kb_b1, kb_m1, kb_v1, kb_g2, kb_b2, kb_m2, kb_v2, biasws);
    repackL_k<<<dim3(72, 1, 1), blk, 0, stream>>>(w_last, wrpL);
    repack7_k<<<dim3(104, 1, 1), blk, 0, stream>>>(w_first, wrp7hi, wrp7lo);
    prep7_k<<<dim3(2048, 1, 1), blk, 0, stream>>>(fm, in7hi, in7lo);

    // conv_first -> actA
    conv7_mfma<<<dim3(2048, 1, 1), blk, 34304, stream>>>(in7hi, in7lo, wrp7hi, wrp7lo, actA);

    // residual blocks (32x32x16, A=pixels B=weights-in-registers, 4-row tile)
    unsigned short* cur = actA;
    unsigned short* oth = actC;
    for (int i = 0; i < 4; ++i) {
        conv3_mfma32<false><<<dim3(1024, 1, 1), dim3(512), 0, stream>>>(
            cur, wrp3n + (size_t)i * 36864, biasws + i * 64, nullptr, actB);
        conv3_mfma32<true><<<dim3(1024, 1, 1), dim3(512), 0, stream>>>(
            actB, wrp3n + (size_t)(4 + i) * 36864, biasws + (4 + i) * 64, cur, oth);
        unsigned short* t = cur; cur = oth; oth = t;
    }

    // conv_last: 64 -> 30, planar30 bf16 logits
    conv3_last<2, 30><<<dim3(2048, 1, 1), blk, 51776, stream>>>(cur, wrpL, logits);

    // fused adaptive filtering
    filt_fused_k<<<dim3(3072, 1, 1), blk, 0, stream>>>(logits, base, (float*)d_out);
}